// Round 1
// baseline (2066.121 us; speedup 1.0000x reference)
//
#include <hip/hip_runtime.h>
#include <hip/hip_bf16.h>
#include <math.h>

#define BQ 8
#define LQ 1024
#define DMODEL 256
#define DINNER 512
#define DSTATE 16
#define NLAYER 4
#define NTOK (BQ * LQ)          // 8192
#define NCAT 576                 // 512 (dt) + 16 (B) + 16 (C) + 32 zero pad

// ---------------- helpers ----------------

__device__ inline float silu_f(float x) { return x / (1.f + __expf(-x)); }

__device__ inline float softplus_f(float x) {
    return (x > 20.f) ? x : log1pf(expf(x));
}

// block-wide mean / rstd over 256 values (one per thread)
__device__ inline float2 block_meanrstd(float v, float* sbuf) {
    float sm = v, sq = v * v;
#pragma unroll
    for (int o = 32; o; o >>= 1) {
        sm += __shfl_xor(sm, o);
        sq += __shfl_xor(sq, o);
    }
    int w = threadIdx.x >> 6;
    if ((threadIdx.x & 63) == 0) { sbuf[w] = sm; sbuf[4 + w] = sq; }
    __syncthreads();
    sm = sbuf[0] + sbuf[1] + sbuf[2] + sbuf[3];
    sq = sbuf[4] + sbuf[5] + sbuf[6] + sbuf[7];
    float m = sm * (1.f / 256.f);
    float var = sq * (1.f / 256.f) - m * m;
    return make_float2(m, rsqrtf(var + 1e-5f));
}

// ---------------- kernels ----------------

// pack W_dt | W_B | W_C | zeros  into [NLAYER][512][576]
__global__ __launch_bounds__(256) void k_pack(const float* __restrict__ Wdt,
                                              const float* __restrict__ WB,
                                              const float* __restrict__ WC,
                                              float* __restrict__ wcat) {
    int i = blockIdx.x * 256 + threadIdx.x;
    if (i >= NLAYER * 512 * NCAT) return;
    int n = i % NCAT;
    int k = (i / NCAT) % 512;
    int l = i / (NCAT * 512);
    float v = 0.f;
    if (n < 512)       v = Wdt[((size_t)l * 512 + k) * 512 + n];
    else if (n < 528)  v = WB[((size_t)l * 512 + k) * 16 + (n - 512)];
    else if (n < 544)  v = WC[((size_t)l * 512 + k) * 16 + (n - 528)];
    wcat[i] = v;
}

// input proj (1x1 conv over 4 channels) + input LayerNorm -> h [NTOK,256]
__global__ __launch_bounds__(256) void k_inproj_ln(const float* __restrict__ x,
                                                   const float* __restrict__ w_in,
                                                   const float* __restrict__ b_in,
                                                   const float* __restrict__ g,
                                                   const float* __restrict__ bt,
                                                   float* __restrict__ h) {
    int tok = blockIdx.x;
    int b = tok >> 10, l = tok & 1023;
    int d = threadIdx.x;
    __shared__ float xs[4];
    __shared__ float sbuf[8];
    if (d < 4) xs[d] = x[((size_t)b * 4 + d) * LQ + l];
    __syncthreads();
    float v = b_in[d];
#pragma unroll
    for (int c = 0; c < 4; c++) v = fmaf(xs[c], w_in[d * 4 + c], v);
    float2 mr = block_meanrstd(v, sbuf);
    h[(size_t)tok * 256 + d] = (v - mr.x) * mr.y * g[d] + bt[d];
}

// per-token LayerNorm: hn = LN(h)*g+b
__global__ __launch_bounds__(256) void k_ln(const float* __restrict__ h,
                                            const float* __restrict__ g,
                                            const float* __restrict__ bt,
                                            float* __restrict__ hn) {
    int tok = blockIdx.x;
    int d = threadIdx.x;
    __shared__ float sbuf[8];
    float v = h[(size_t)tok * 256 + d];
    float2 mr = block_meanrstd(v, sbuf);
    hn[(size_t)tok * 256 + d] = (v - mr.x) * mr.y * g[d] + bt[d];
}

// fp32 tiled GEMM  C[M,N] (+epi) = A[M,K] * B[K,N]
// EPI 0: plain store to C
// EPI 1: split epilogue: col<512 -> dt=softplus(v+bias[col]); 512..527 -> Bin; 528..543 -> Cin
// EPI 2: C += A*B  (residual accumulate)
template <int EPI>
__global__ __launch_bounds__(256) void k_gemm(const float* __restrict__ A,
                                              const float* __restrict__ Bm,
                                              float* __restrict__ C,
                                              const float* __restrict__ bias,
                                              float* __restrict__ outB,
                                              float* __restrict__ outC,
                                              int M, int N, int K) {
    __shared__ float As[8][128];
    __shared__ float Bs[8][128];
    const int tid = threadIdx.x;
    const int bm = blockIdx.x * 128;
    const int bn = blockIdx.y * 128;

    float acc[8][8];
#pragma unroll
    for (int i = 0; i < 8; i++)
#pragma unroll
        for (int j = 0; j < 8; j++) acc[i][j] = 0.f;

    const int ar = tid >> 1;          // 0..127
    const int ak = (tid & 1) * 4;     // 0 or 4
    const int bk = tid >> 5;          // 0..7
    const int bn4 = (tid & 31) * 4;   // 0..124
    const int gn = bn + bn4;

    const float* Aptr = A + (size_t)(bm + ar) * K + ak;
    const float* Bptr = Bm + (size_t)bk * N + gn;

    const int tm = (tid >> 4) * 8;
    const int tn = (tid & 15) * 8;

    for (int k0 = 0; k0 < K; k0 += 8) {
        float4 av = *(const float4*)(Aptr + k0);
        float4 bv = make_float4(0.f, 0.f, 0.f, 0.f);
        if (gn < N) bv = *(const float4*)(Bptr + (size_t)k0 * N);
        __syncthreads();
        As[ak + 0][ar] = av.x;
        As[ak + 1][ar] = av.y;
        As[ak + 2][ar] = av.z;
        As[ak + 3][ar] = av.w;
        *(float4*)&Bs[bk][bn4] = bv;
        __syncthreads();
#pragma unroll
        for (int kk = 0; kk < 8; kk++) {
            float a[8], b[8];
            *(float4*)&a[0] = *(const float4*)&As[kk][tm];
            *(float4*)&a[4] = *(const float4*)&As[kk][tm + 4];
            *(float4*)&b[0] = *(const float4*)&Bs[kk][tn];
            *(float4*)&b[4] = *(const float4*)&Bs[kk][tn + 4];
#pragma unroll
            for (int i = 0; i < 8; i++)
#pragma unroll
                for (int j = 0; j < 8; j++)
                    acc[i][j] = fmaf(a[i], b[j], acc[i][j]);
        }
    }

    if (EPI == 0) {
#pragma unroll
        for (int i = 0; i < 8; i++) {
            float4* cp = (float4*)&C[(size_t)(bm + tm + i) * N + bn + tn];
            cp[0] = make_float4(acc[i][0], acc[i][1], acc[i][2], acc[i][3]);
            cp[1] = make_float4(acc[i][4], acc[i][5], acc[i][6], acc[i][7]);
        }
    } else if (EPI == 1) {
#pragma unroll
        for (int i = 0; i < 8; i++) {
            int row = bm + tm + i;
#pragma unroll
            for (int j = 0; j < 8; j++) {
                int col = bn + tn + j;
                float v = acc[i][j];
                if (col < 512) {
                    C[(size_t)row * 512 + col] = softplus_f(v + bias[col]);
                } else if (col < 528) {
                    outB[(size_t)row * 16 + (col - 512)] = v;
                } else if (col < 544) {
                    outC[(size_t)row * 16 + (col - 528)] = v;
                }
            }
        }
    } else {  // EPI == 2, residual accumulate into C
#pragma unroll
        for (int i = 0; i < 8; i++) {
            float4* cp = (float4*)&C[(size_t)(bm + tm + i) * N + bn + tn];
            float4 c0 = cp[0], c1 = cp[1];
            c0.x += acc[i][0]; c0.y += acc[i][1]; c0.z += acc[i][2]; c0.w += acc[i][3];
            c1.x += acc[i][4]; c1.y += acc[i][5]; c1.z += acc[i][6]; c1.w += acc[i][7];
            cp[0] = c0; cp[1] = c1;
        }
    }
}

// causal depthwise conv (k=4, left pad 3) + bias + SiLU.  xz x-half -> x_ssm
__global__ __launch_bounds__(256) void k_conv(const float* __restrict__ xz,
                                              const float* __restrict__ cw,
                                              const float* __restrict__ cb,
                                              float* __restrict__ xs_out) {
    int i = blockIdx.x * 256 + threadIdx.x;   // over NTOK*512
    int d = i & 511;
    int tok = i >> 9;
    int l = tok & 1023;
    int b = tok >> 10;
    float w0 = cw[d * 4 + 0], w1 = cw[d * 4 + 1], w2 = cw[d * 4 + 2], w3 = cw[d * 4 + 3];
    float accv = cb[d];
    const float* base = xz + ((size_t)b * 1024) * 1024 + d;
    if (l >= 3) {
        accv = fmaf(base[(size_t)(l - 3) * 1024], w0, accv);
        accv = fmaf(base[(size_t)(l - 2) * 1024], w1, accv);
        accv = fmaf(base[(size_t)(l - 1) * 1024], w2, accv);
        accv = fmaf(base[(size_t)l * 1024],       w3, accv);
    } else {
        if (l >= 3) accv = fmaf(base[(size_t)(l - 3) * 1024], w0, accv);
        if (l >= 2) accv = fmaf(base[(size_t)(l - 2) * 1024], w1, accv);
        if (l >= 1) accv = fmaf(base[(size_t)(l - 1) * 1024], w2, accv);
        accv = fmaf(base[(size_t)l * 1024], w3, accv);
    }
    xs_out[(size_t)tok * 512 + d] = silu_f(accv);
}

// selective scan.  block: 256 thr = 16 d-channels x 16 states, one (b, d-group)
__global__ __launch_bounds__(256) void k_scan(const float* __restrict__ xs,
                                              const float* __restrict__ dt,
                                              const float* __restrict__ Bin,
                                              const float* __restrict__ Cin,
                                              const float* __restrict__ A_log,
                                              float* __restrict__ y) {
    int b = blockIdx.x >> 5;
    int dg = blockIdx.x & 31;
    int tid = threadIdx.x;
    int s = tid & 15;
    int dl = tid >> 4;
    int d = dg * 16 + dl;

    float Av = -expf(A_log[(size_t)d * 16 + s]);
    float h = 0.f;

    const float* dt_p = dt + (size_t)b * 1024 * 512 + d;
    const float* x_p  = xs + (size_t)b * 1024 * 512 + d;
    const float* B_p  = Bin + (size_t)b * 1024 * 16 + s;
    const float* C_p  = Cin + (size_t)b * 1024 * 16 + s;
    float* y_p        = y + (size_t)b * 1024 * 512 + d;

    const int U = 8;
    for (int t = 0; t < 1024; t += U) {
        float dtv[U], xv[U], bv[U], cv[U];
#pragma unroll
        for (int j = 0; j < U; j++) {
            dtv[j] = dt_p[(size_t)(t + j) * 512];
            xv[j]  = x_p[(size_t)(t + j) * 512];
            bv[j]  = B_p[(size_t)(t + j) * 16];
            cv[j]  = C_p[(size_t)(t + j) * 16];
        }
#pragma unroll
        for (int j = 0; j < U; j++) {
            float a = __expf(Av * dtv[j]);
            h = fmaf(a, h, dtv[j] * xv[j] * bv[j]);
            float yp = h * cv[j];
            yp += __shfl_xor(yp, 1);
            yp += __shfl_xor(yp, 2);
            yp += __shfl_xor(yp, 4);
            yp += __shfl_xor(yp, 8);
            if (s == 0) y_p[(size_t)(t + j) * 512] = yp;
        }
    }
}

// y = (y + D*x_ssm) * silu(z)
__global__ __launch_bounds__(256) void k_gate(float* __restrict__ y,
                                              const float* __restrict__ xs,
                                              const float* __restrict__ xz,
                                              const float* __restrict__ Dv) {
    int i = blockIdx.x * 256 + threadIdx.x;  // NTOK*512
    int d = i & 511;
    int tok = i >> 9;
    float z = xz[(size_t)tok * 1024 + 512 + d];
    y[i] = (y[i] + Dv[d] * xs[i]) * silu_f(z);
}

// per-token mean/rstd for final LN
__global__ __launch_bounds__(256) void k_stats(const float* __restrict__ h,
                                               float2* __restrict__ stats) {
    int tok = blockIdx.x * 4 + (threadIdx.x >> 6);
    int lane = threadIdx.x & 63;
    float4 v = *(const float4*)&h[(size_t)tok * 256 + lane * 4];
    float sm = v.x + v.y + v.z + v.w;
    float sq = v.x * v.x + v.y * v.y + v.z * v.z + v.w * v.w;
#pragma unroll
    for (int o = 32; o; o >>= 1) {
        sm += __shfl_xor(sm, o);
        sq += __shfl_xor(sq, o);
    }
    if (lane == 0) {
        float m = sm * (1.f / 256.f);
        float var = sq * (1.f / 256.f) - m * m;
        stats[tok] = make_float2(m, rsqrtf(var + 1e-5f));
    }
}

// out[b,d] = mean_l( LN(h)*g+b ) ; grid = 8 b * 8 chunks
__global__ __launch_bounds__(256) void k_out(const float* __restrict__ h,
                                             const float2* __restrict__ stats,
                                             const float* __restrict__ g,
                                             const float* __restrict__ bias,
                                             float* __restrict__ out) {
    int b = blockIdx.x >> 3;
    int chunk = blockIdx.x & 7;
    int d = threadIdx.x;
    float accv = 0.f;
    for (int l = chunk * 128; l < chunk * 128 + 128; l++) {
        float2 st = stats[b * 1024 + l];
        accv += (h[((size_t)b * 1024 + l) * 256 + d] - st.x) * st.y;
    }
    float res = accv * g[d] * (1.f / 1024.f);
    if (chunk == 0) res += bias[d];
    atomicAdd(&out[b * 256 + d], res);
}

// ---------------- launch ----------------

extern "C" void kernel_launch(void* const* d_in, const int* in_sizes, int n_in,
                              void* d_out, int out_size, void* d_ws, size_t ws_size,
                              hipStream_t stream) {
    const float* x       = (const float*)d_in[0];
    const float* w_in    = (const float*)d_in[1];
    const float* b_in    = (const float*)d_in[2];
    const float* ln_in_g = (const float*)d_in[3];
    const float* ln_in_b = (const float*)d_in[4];
    const float* ln_g    = (const float*)d_in[5];
    const float* ln_b    = (const float*)d_in[6];
    const float* W_inproj= (const float*)d_in[7];
    const float* conv_w  = (const float*)d_in[8];
    const float* conv_b  = (const float*)d_in[9];
    const float* W_dt    = (const float*)d_in[10];
    const float* b_dt    = (const float*)d_in[11];
    const float* W_B     = (const float*)d_in[12];
    const float* W_C     = (const float*)d_in[13];
    const float* A_log   = (const float*)d_in[14];
    const float* Dp      = (const float*)d_in[15];
    const float* W_out   = (const float*)d_in[16];
    const float* ln_f_g  = (const float*)d_in[17];
    const float* ln_f_b  = (const float*)d_in[18];

    float* out = (float*)d_out;
    float* ws = (float*)d_ws;

    float* wcat = ws;                                   // 4*512*576  = 1,179,648
    float* h    = wcat + (size_t)NLAYER * 512 * NCAT;   // 2,097,152
    float* hn   = h + (size_t)NTOK * 256;               // 2,097,152
    float* xz   = hn + (size_t)NTOK * 256;              // 8,388,608
    float* xs   = xz + (size_t)NTOK * 1024;             // 4,194,304
    float* dtb  = xs + (size_t)NTOK * 512;              // 4,194,304
    float* Bin  = dtb + (size_t)NTOK * 512;             // 131,072
    float* Cin  = Bin + (size_t)NTOK * 16;              // 131,072
    float* yb   = Cin + (size_t)NTOK * 16;              // 4,194,304
    float2* stats = (float2*)(yb + (size_t)NTOK * 512); // 8192 float2

    hipMemsetAsync(d_out, 0, (size_t)out_size * sizeof(float), stream);

    {
        int n = NLAYER * 512 * NCAT;
        k_pack<<<(n + 255) / 256, 256, 0, stream>>>(W_dt, W_B, W_C, wcat);
    }
    k_inproj_ln<<<NTOK, 256, 0, stream>>>(x, w_in, b_in, ln_in_g, ln_in_b, h);

    for (int l = 0; l < NLAYER; l++) {
        k_ln<<<NTOK, 256, 0, stream>>>(h, ln_g + l * 256, ln_b + l * 256, hn);

        dim3 g1(NTOK / 128, 1024 / 128);
        k_gemm<0><<<g1, 256, 0, stream>>>(hn, W_inproj + (size_t)l * 256 * 1024, xz,
                                          nullptr, nullptr, nullptr, NTOK, 1024, 256);

        k_conv<<<(NTOK * 512) / 256, 256, 0, stream>>>(xz, conv_w + (size_t)l * 512 * 4,
                                                       conv_b + (size_t)l * 512, xs);

        dim3 g2(NTOK / 128, (NCAT + 127) / 128);
        k_gemm<1><<<g2, 256, 0, stream>>>(xs, wcat + (size_t)l * 512 * NCAT, dtb,
                                          b_dt + (size_t)l * 512, Bin, Cin, NTOK, NCAT, 512);

        k_scan<<<256, 256, 0, stream>>>(xs, dtb, Bin, Cin,
                                        A_log + (size_t)l * 512 * 16, yb);

        k_gate<<<(NTOK * 512) / 256, 256, 0, stream>>>(yb, xs, xz, Dp + (size_t)l * 512);

        dim3 g3(NTOK / 128, 256 / 128);
        k_gemm<2><<<g3, 256, 0, stream>>>(yb, W_out + (size_t)l * 512 * 256, h,
                                          nullptr, nullptr, nullptr, NTOK, 256, 512);
    }

    k_stats<<<NTOK / 4, 256, 0, stream>>>(h, stats);
    k_out<<<64, 256, 0, stream>>>(h, stats, ln_f_g, ln_f_b, out);
}

// Round 2
// 1859.082 us; speedup vs baseline: 1.1114x; 1.1114x over previous
//
#include <hip/hip_runtime.h>
#include <hip/hip_bf16.h>
#include <math.h>

#define BQ 8
#define LQ 1024
#define DMODEL 256
#define DINNER 512
#define DSTATE 16
#define NLAYER 4
#define NTOK (BQ * LQ)          // 8192
#define NCAT 576                 // 512 (dt) + 16 (B) + 16 (C) + 32 zero pad
#define NCHUNK 8
#define CHLEN 128

// ---------------- helpers ----------------

__device__ inline float silu_f(float x) { return x / (1.f + __expf(-x)); }

__device__ inline float softplus_f(float x) {
    return (x > 20.f) ? x : log1pf(expf(x));
}

// block-wide mean / rstd over 256 values (one per thread)
__device__ inline float2 block_meanrstd(float v, float* sbuf) {
    float sm = v, sq = v * v;
#pragma unroll
    for (int o = 32; o; o >>= 1) {
        sm += __shfl_xor(sm, o);
        sq += __shfl_xor(sq, o);
    }
    int w = threadIdx.x >> 6;
    if ((threadIdx.x & 63) == 0) { sbuf[w] = sm; sbuf[4 + w] = sq; }
    __syncthreads();
    sm = sbuf[0] + sbuf[1] + sbuf[2] + sbuf[3];
    sq = sbuf[4] + sbuf[5] + sbuf[6] + sbuf[7];
    float m = sm * (1.f / 256.f);
    float var = sq * (1.f / 256.f) - m * m;
    return make_float2(m, rsqrtf(var + 1e-5f));
}

// ---------------- kernels ----------------

// pack W_dt | W_B | W_C | zeros  into [NLAYER][512][576]
__global__ __launch_bounds__(256) void k_pack(const float* __restrict__ Wdt,
                                              const float* __restrict__ WB,
                                              const float* __restrict__ WC,
                                              float* __restrict__ wcat) {
    int i = blockIdx.x * 256 + threadIdx.x;
    if (i >= NLAYER * 512 * NCAT) return;
    int n = i % NCAT;
    int k = (i / NCAT) % 512;
    int l = i / (NCAT * 512);
    float v = 0.f;
    if (n < 512)       v = Wdt[((size_t)l * 512 + k) * 512 + n];
    else if (n < 528)  v = WB[((size_t)l * 512 + k) * 16 + (n - 512)];
    else if (n < 544)  v = WC[((size_t)l * 512 + k) * 16 + (n - 528)];
    wcat[i] = v;
}

// input proj (1x1 conv over 4 channels) + input LayerNorm -> h [NTOK,256]
__global__ __launch_bounds__(256) void k_inproj_ln(const float* __restrict__ x,
                                                   const float* __restrict__ w_in,
                                                   const float* __restrict__ b_in,
                                                   const float* __restrict__ g,
                                                   const float* __restrict__ bt,
                                                   float* __restrict__ h) {
    int tok = blockIdx.x;
    int b = tok >> 10, l = tok & 1023;
    int d = threadIdx.x;
    __shared__ float xs[4];
    __shared__ float sbuf[8];
    if (d < 4) xs[d] = x[((size_t)b * 4 + d) * LQ + l];
    __syncthreads();
    float v = b_in[d];
#pragma unroll
    for (int c = 0; c < 4; c++) v = fmaf(xs[c], w_in[d * 4 + c], v);
    float2 mr = block_meanrstd(v, sbuf);
    h[(size_t)tok * 256 + d] = (v - mr.x) * mr.y * g[d] + bt[d];
}

// per-token LayerNorm: hn = LN(h)*g+b
__global__ __launch_bounds__(256) void k_ln(const float* __restrict__ h,
                                            const float* __restrict__ g,
                                            const float* __restrict__ bt,
                                            float* __restrict__ hn) {
    int tok = blockIdx.x;
    int d = threadIdx.x;
    __shared__ float sbuf[8];
    float v = h[(size_t)tok * 256 + d];
    float2 mr = block_meanrstd(v, sbuf);
    hn[(size_t)tok * 256 + d] = (v - mr.x) * mr.y * g[d] + bt[d];
}

// fp32 tiled GEMM  C[M,N] (+epi) = A[M,K] * B[K,N]
template <int EPI>
__global__ __launch_bounds__(256) void k_gemm(const float* __restrict__ A,
                                              const float* __restrict__ Bm,
                                              float* __restrict__ C,
                                              const float* __restrict__ bias,
                                              float* __restrict__ outB,
                                              float* __restrict__ outC,
                                              int M, int N, int K) {
    __shared__ float As[8][128];
    __shared__ float Bs[8][128];
    const int tid = threadIdx.x;
    const int bm = blockIdx.x * 128;
    const int bn = blockIdx.y * 128;

    float acc[8][8];
#pragma unroll
    for (int i = 0; i < 8; i++)
#pragma unroll
        for (int j = 0; j < 8; j++) acc[i][j] = 0.f;

    const int ar = tid >> 1;          // 0..127
    const int ak = (tid & 1) * 4;     // 0 or 4
    const int bk = tid >> 5;          // 0..7
    const int bn4 = (tid & 31) * 4;   // 0..124
    const int gn = bn + bn4;

    const float* Aptr = A + (size_t)(bm + ar) * K + ak;
    const float* Bptr = Bm + (size_t)bk * N + gn;

    const int tm = (tid >> 4) * 8;
    const int tn = (tid & 15) * 8;

    for (int k0 = 0; k0 < K; k0 += 8) {
        float4 av = *(const float4*)(Aptr + k0);
        float4 bv = make_float4(0.f, 0.f, 0.f, 0.f);
        if (gn < N) bv = *(const float4*)(Bptr + (size_t)k0 * N);
        __syncthreads();
        As[ak + 0][ar] = av.x;
        As[ak + 1][ar] = av.y;
        As[ak + 2][ar] = av.z;
        As[ak + 3][ar] = av.w;
        *(float4*)&Bs[bk][bn4] = bv;
        __syncthreads();
#pragma unroll
        for (int kk = 0; kk < 8; kk++) {
            float a[8], b[8];
            *(float4*)&a[0] = *(const float4*)&As[kk][tm];
            *(float4*)&a[4] = *(const float4*)&As[kk][tm + 4];
            *(float4*)&b[0] = *(const float4*)&Bs[kk][tn];
            *(float4*)&b[4] = *(const float4*)&Bs[kk][tn + 4];
#pragma unroll
            for (int i = 0; i < 8; i++)
#pragma unroll
                for (int j = 0; j < 8; j++)
                    acc[i][j] = fmaf(a[i], b[j], acc[i][j]);
        }
    }

    if (EPI == 0) {
#pragma unroll
        for (int i = 0; i < 8; i++) {
            float4* cp = (float4*)&C[(size_t)(bm + tm + i) * N + bn + tn];
            cp[0] = make_float4(acc[i][0], acc[i][1], acc[i][2], acc[i][3]);
            cp[1] = make_float4(acc[i][4], acc[i][5], acc[i][6], acc[i][7]);
        }
    } else if (EPI == 1) {
#pragma unroll
        for (int i = 0; i < 8; i++) {
            int row = bm + tm + i;
#pragma unroll
            for (int j = 0; j < 8; j++) {
                int col = bn + tn + j;
                float v = acc[i][j];
                if (col < 512) {
                    C[(size_t)row * 512 + col] = softplus_f(v + bias[col]);
                } else if (col < 528) {
                    outB[(size_t)row * 16 + (col - 512)] = v;
                } else if (col < 544) {
                    outC[(size_t)row * 16 + (col - 528)] = v;
                }
            }
        }
    } else {  // EPI == 2, residual accumulate into C
#pragma unroll
        for (int i = 0; i < 8; i++) {
            float4* cp = (float4*)&C[(size_t)(bm + tm + i) * N + bn + tn];
            float4 c0 = cp[0], c1 = cp[1];
            c0.x += acc[i][0]; c0.y += acc[i][1]; c0.z += acc[i][2]; c0.w += acc[i][3];
            c1.x += acc[i][4]; c1.y += acc[i][5]; c1.z += acc[i][6]; c1.w += acc[i][7];
            cp[0] = c0; cp[1] = c1;
        }
    }
}

// causal depthwise conv (k=4, left pad 3) + bias + SiLU.  xz x-half -> x_ssm
__global__ __launch_bounds__(256) void k_conv(const float* __restrict__ xz,
                                              const float* __restrict__ cw,
                                              const float* __restrict__ cb,
                                              float* __restrict__ xs_out) {
    int i = blockIdx.x * 256 + threadIdx.x;   // over NTOK*512
    int d = i & 511;
    int tok = i >> 9;
    int l = tok & 1023;
    int b = tok >> 10;
    float w0 = cw[d * 4 + 0], w1 = cw[d * 4 + 1], w2 = cw[d * 4 + 2], w3 = cw[d * 4 + 3];
    float accv = cb[d];
    const float* base = xz + ((size_t)b * 1024) * 1024 + d;
    if (l >= 3) {
        accv = fmaf(base[(size_t)(l - 3) * 1024], w0, accv);
        accv = fmaf(base[(size_t)(l - 2) * 1024], w1, accv);
        accv = fmaf(base[(size_t)(l - 1) * 1024], w2, accv);
        accv = fmaf(base[(size_t)l * 1024],       w3, accv);
    } else {
        if (l >= 2) accv = fmaf(base[(size_t)(l - 2) * 1024], w1, accv);
        if (l >= 1) accv = fmaf(base[(size_t)(l - 1) * 1024], w2, accv);
        accv = fmaf(base[(size_t)l * 1024], w3, accv);
    }
    xs_out[(size_t)tok * 512 + d] = silu_f(accv);
}

// ---- chunked selective scan ----
// thread layout (256 thr): wave = tid>>6, lane = tid&63, s = lane&15,
// d_local = wave*4 + (lane>>4)  (0..15), d = dg*16 + d_local
// grid: b(8) x chunk(8) x dgroup(32) = 2048 blocks

// pass 1: local scan (h0 = 0) within each 128-step chunk
__global__ __launch_bounds__(256) void k_scan1(const float* __restrict__ xs,
                                               const float* __restrict__ dt,
                                               const float* __restrict__ Bin,
                                               const float* __restrict__ Cin,
                                               const float* __restrict__ A_log,
                                               float* __restrict__ y,
                                               float* __restrict__ h_end,
                                               float* __restrict__ dtsum) {
    int bx = blockIdx.x;
    int dg = bx & 31;
    int c  = (bx >> 5) & 7;
    int b  = bx >> 8;
    int tid = threadIdx.x;
    int lane = tid & 63;
    int wave = tid >> 6;
    int s = lane & 15;
    int d = dg * 16 + wave * 4 + (lane >> 4);

    float Av = -__expf(A_log[d * 16 + s]);
    float h = 0.f, dts = 0.f;

    const size_t tok0 = (size_t)b * 1024 + (size_t)c * CHLEN;
    const float* dt_p = dt + tok0 * 512 + d;
    const float* x_p  = xs + tok0 * 512 + d;
    const float* B_p  = Bin + tok0 * 16 + s;
    const float* C_p  = Cin + tok0 * 16 + s;
    float* y_p        = y + tok0 * 512 + d;

    const int U = 4;
    for (int t = 0; t < CHLEN; t += U) {
        float dtv[U], xv[U], bv[U], cv[U];
#pragma unroll
        for (int j = 0; j < U; j++) {
            dtv[j] = dt_p[(size_t)(t + j) * 512];
            xv[j]  = x_p[(size_t)(t + j) * 512];
            bv[j]  = B_p[(size_t)(t + j) * 16];
            cv[j]  = C_p[(size_t)(t + j) * 16];
        }
#pragma unroll
        for (int j = 0; j < U; j++) {
            float a = __expf(Av * dtv[j]);
            h = fmaf(a, h, dtv[j] * xv[j] * bv[j]);
            dts += dtv[j];
            float yp = h * cv[j];
            yp += __shfl_xor(yp, 1);
            yp += __shfl_xor(yp, 2);
            yp += __shfl_xor(yp, 4);
            yp += __shfl_xor(yp, 8);
            if (s == 0) y_p[(size_t)(t + j) * 512] = yp;
        }
    }
    size_t cidx = (size_t)(b * NCHUNK + c) * 512 + d;
    h_end[cidx * 16 + s] = h;
    if (s == 0) dtsum[cidx] = dts;
}

// pass 2: serial carry across 8 chunks per (b,d,s): H_in[c] = state entering chunk c
__global__ __launch_bounds__(256) void k_carry(const float* __restrict__ h_end,
                                               const float* __restrict__ dtsum,
                                               const float* __restrict__ A_log,
                                               float* __restrict__ H_in) {
    int idx = blockIdx.x * 256 + threadIdx.x;  // 65536 = 8*512*16
    int s = idx & 15;
    int d = (idx >> 4) & 511;
    int b = idx >> 13;
    float Av = -__expf(A_log[d * 16 + s]);
    float H = 0.f;
#pragma unroll
    for (int c = 0; c < NCHUNK; c++) {
        size_t cidx = (size_t)(b * NCHUNK + c) * 512 + d;
        H_in[cidx * 16 + s] = H;
        H = fmaf(__expf(Av * dtsum[cidx]), H, h_end[cidx * 16 + s]);
    }
}

// pass 3: add cross-chunk correction C_t . (exp(A*cumdt_t) * H_in), fused gate:
// y = (y_local + corr + D*x) * silu(z)
__global__ __launch_bounds__(256) void k_scan2(const float* __restrict__ dt,
                                               const float* __restrict__ Cin,
                                               const float* __restrict__ A_log,
                                               const float* __restrict__ H_in,
                                               const float* __restrict__ xs,
                                               const float* __restrict__ xz,
                                               const float* __restrict__ Dv,
                                               float* __restrict__ y) {
    int bx = blockIdx.x;
    int dg = bx & 31;
    int c  = (bx >> 5) & 7;
    int b  = bx >> 8;
    int tid = threadIdx.x;
    int lane = tid & 63;
    int wave = tid >> 6;
    int s = lane & 15;
    int d = dg * 16 + wave * 4 + (lane >> 4);

    float Av = -__expf(A_log[d * 16 + s]);
    size_t cidx = (size_t)(b * NCHUNK + c) * 512 + d;
    float H = H_in[cidx * 16 + s];
    bool haveH = __any(H != 0.f);
    float Dd = Dv[d];

    const size_t tok0 = (size_t)b * 1024 + (size_t)c * CHLEN;
    const float* dt_p = dt + tok0 * 512 + d;
    const float* C_p  = Cin + tok0 * 16 + s;
    const float* x_p  = xs + tok0 * 512 + d;
    const float* z_p  = xz + tok0 * 1024 + 512 + d;
    float* y_p        = y + tok0 * 512 + d;

    float cumdt = 0.f;
    const int U = 4;
    for (int t = 0; t < CHLEN; t += U) {
        float dtv[U], cv[U];
#pragma unroll
        for (int j = 0; j < U; j++) {
            dtv[j] = dt_p[(size_t)(t + j) * 512];
            cv[j]  = C_p[(size_t)(t + j) * 16];
        }
#pragma unroll
        for (int j = 0; j < U; j++) {
            cumdt += dtv[j];
            float corr = 0.f;
            if (haveH) {
                corr = __expf(Av * cumdt) * H * cv[j];
                corr += __shfl_xor(corr, 1);
                corr += __shfl_xor(corr, 2);
                corr += __shfl_xor(corr, 4);
                corr += __shfl_xor(corr, 8);
            }
            if (s == 0) {
                size_t off = (size_t)(t + j) * 512;
                float xsv = x_p[off];
                float zv  = z_p[(size_t)(t + j) * 1024];
                float yl  = y_p[off];
                y_p[off] = (yl + corr + Dd * xsv) * silu_f(zv);
            }
        }
    }
}

// per-token mean/rstd for final LN
__global__ __launch_bounds__(256) void k_stats(const float* __restrict__ h,
                                               float2* __restrict__ stats) {
    int tok = blockIdx.x * 4 + (threadIdx.x >> 6);
    int lane = threadIdx.x & 63;
    float4 v = *(const float4*)&h[(size_t)tok * 256 + lane * 4];
    float sm = v.x + v.y + v.z + v.w;
    float sq = v.x * v.x + v.y * v.y + v.z * v.z + v.w * v.w;
#pragma unroll
    for (int o = 32; o; o >>= 1) {
        sm += __shfl_xor(sm, o);
        sq += __shfl_xor(sq, o);
    }
    if (lane == 0) {
        float m = sm * (1.f / 256.f);
        float var = sq * (1.f / 256.f) - m * m;
        stats[tok] = make_float2(m, rsqrtf(var + 1e-5f));
    }
}

// out[b,d] = mean_l( LN(h)*g+b ) ; grid = 8 b * 8 chunks
__global__ __launch_bounds__(256) void k_out(const float* __restrict__ h,
                                             const float2* __restrict__ stats,
                                             const float* __restrict__ g,
                                             const float* __restrict__ bias,
                                             float* __restrict__ out) {
    int b = blockIdx.x >> 3;
    int chunk = blockIdx.x & 7;
    int d = threadIdx.x;
    float accv = 0.f;
    for (int l = chunk * 128; l < chunk * 128 + 128; l++) {
        float2 st = stats[b * 1024 + l];
        accv += (h[((size_t)b * 1024 + l) * 256 + d] - st.x) * st.y;
    }
    float res = accv * g[d] * (1.f / 1024.f);
    if (chunk == 0) res += bias[d];
    atomicAdd(&out[b * 256 + d], res);
}

// ---------------- launch ----------------

extern "C" void kernel_launch(void* const* d_in, const int* in_sizes, int n_in,
                              void* d_out, int out_size, void* d_ws, size_t ws_size,
                              hipStream_t stream) {
    const float* x       = (const float*)d_in[0];
    const float* w_in    = (const float*)d_in[1];
    const float* b_in    = (const float*)d_in[2];
    const float* ln_in_g = (const float*)d_in[3];
    const float* ln_in_b = (const float*)d_in[4];
    const float* ln_g    = (const float*)d_in[5];
    const float* ln_b    = (const float*)d_in[6];
    const float* W_inproj= (const float*)d_in[7];
    const float* conv_w  = (const float*)d_in[8];
    const float* conv_b  = (const float*)d_in[9];
    const float* W_dt    = (const float*)d_in[10];
    const float* b_dt    = (const float*)d_in[11];
    const float* W_B     = (const float*)d_in[12];
    const float* W_C     = (const float*)d_in[13];
    const float* A_log   = (const float*)d_in[14];
    const float* Dp      = (const float*)d_in[15];
    const float* W_out   = (const float*)d_in[16];
    const float* ln_f_g  = (const float*)d_in[17];
    const float* ln_f_b  = (const float*)d_in[18];

    float* out = (float*)d_out;
    float* ws = (float*)d_ws;

    float* wcat = ws;                                   // 4*512*576
    float* h    = wcat + (size_t)NLAYER * 512 * NCAT;
    float* hn   = h + (size_t)NTOK * 256;
    float* xz   = hn + (size_t)NTOK * 256;
    float* xs   = xz + (size_t)NTOK * 1024;
    float* dtb  = xs + (size_t)NTOK * 512;
    float* Bin  = dtb + (size_t)NTOK * 512;
    float* Cin  = Bin + (size_t)NTOK * 16;
    float* yb   = Cin + (size_t)NTOK * 16;
    float2* stats = (float2*)(yb + (size_t)NTOK * 512);
    float* h_end = (float*)(stats + NTOK);              // 8*8*512*16
    float* H_in  = h_end + (size_t)BQ * NCHUNK * 512 * 16;
    float* dtsum = H_in + (size_t)BQ * NCHUNK * 512 * 16; // 8*8*512

    hipMemsetAsync(d_out, 0, (size_t)out_size * sizeof(float), stream);

    {
        int n = NLAYER * 512 * NCAT;
        k_pack<<<(n + 255) / 256, 256, 0, stream>>>(W_dt, W_B, W_C, wcat);
    }
    k_inproj_ln<<<NTOK, 256, 0, stream>>>(x, w_in, b_in, ln_in_g, ln_in_b, h);

    for (int l = 0; l < NLAYER; l++) {
        k_ln<<<NTOK, 256, 0, stream>>>(h, ln_g + l * 256, ln_b + l * 256, hn);

        dim3 g1(NTOK / 128, 1024 / 128);
        k_gemm<0><<<g1, 256, 0, stream>>>(hn, W_inproj + (size_t)l * 256 * 1024, xz,
                                          nullptr, nullptr, nullptr, NTOK, 1024, 256);

        k_conv<<<(NTOK * 512) / 256, 256, 0, stream>>>(xz, conv_w + (size_t)l * 512 * 4,
                                                       conv_b + (size_t)l * 512, xs);

        dim3 g2(NTOK / 128, (NCAT + 127) / 128);
        k_gemm<1><<<g2, 256, 0, stream>>>(xs, wcat + (size_t)l * 512 * NCAT, dtb,
                                          b_dt + (size_t)l * 512, Bin, Cin, NTOK, NCAT, 512);

        const float* Al = A_log + (size_t)l * 512 * 16;
        k_scan1<<<2048, 256, 0, stream>>>(xs, dtb, Bin, Cin, Al, yb, h_end, dtsum);
        k_carry<<<256, 256, 0, stream>>>(h_end, dtsum, Al, H_in);
        k_scan2<<<2048, 256, 0, stream>>>(dtb, Cin, Al, H_in, xs, xz, Dp + (size_t)l * 512, yb);

        dim3 g3(NTOK / 128, 256 / 128);
        k_gemm<2><<<g3, 256, 0, stream>>>(yb, W_out + (size_t)l * 512 * 256, h,
                                          nullptr, nullptr, nullptr, NTOK, 256, 512);
    }

    k_stats<<<NTOK / 4, 256, 0, stream>>>(h, stats);
    k_out<<<64, 256, 0, stream>>>(h, stats, ln_f_g, ln_f_b, out);
}

// Round 3
// 1139.409 us; speedup vs baseline: 1.8133x; 1.6316x over previous
//
#include <hip/hip_runtime.h>
#include <hip/hip_bf16.h>
#include <math.h>

#define BQ 8
#define LQ 1024
#define DMODEL 256
#define DINNER 512
#define DSTATE 16
#define NLAYER 4
#define NTOK (BQ * LQ)          // 8192
#define NCHUNK 8
#define CHLEN 128

typedef __attribute__((ext_vector_type(8))) short short8v;
typedef __attribute__((ext_vector_type(4))) float float4v;

// ---------------- helpers ----------------

__device__ inline float silu_f(float x) { return x / (1.f + __expf(-x)); }

__device__ inline float softplus_f(float x) {
    return (x > 20.f) ? x : log1pf(expf(x));
}

__device__ __forceinline__ void gl_lds16(const void* g, void* l) {
    __builtin_amdgcn_global_load_lds(
        (const __attribute__((address_space(1))) unsigned int*)g,
        (__attribute__((address_space(3))) unsigned int*)l,
        16, 0, 0);
}

// block-wide mean / rstd over 256 values (one per thread)
__device__ inline float2 block_meanrstd(float v, float* sbuf) {
    float sm = v, sq = v * v;
#pragma unroll
    for (int o = 32; o; o >>= 1) {
        sm += __shfl_xor(sm, o);
        sq += __shfl_xor(sq, o);
    }
    int w = threadIdx.x >> 6;
    if ((threadIdx.x & 63) == 0) { sbuf[w] = sm; sbuf[4 + w] = sq; }
    __syncthreads();
    sm = sbuf[0] + sbuf[1] + sbuf[2] + sbuf[3];
    sq = sbuf[4] + sbuf[5] + sbuf[6] + sbuf[7];
    float m = sm * (1.f / 256.f);
    float var = sq * (1.f / 256.f) - m * m;
    return make_float2(m, rsqrtf(var + 1e-5f));
}

// ---------------- weight prep ----------------

// transpose+cast: in [z][K][N] fp32 -> out [z][N][K] bf16 (out may point mid-buffer; layer
// stride outLS). K multiple of 32. N arbitrary (<=32*gridDim.y).
__global__ __launch_bounds__(256) void k_tr(const float* __restrict__ in,
                                            __hip_bfloat16* __restrict__ out,
                                            int K, int N, int inLS, int outLS) {
    __shared__ float t[32][33];
    const float* inp = in + (size_t)blockIdx.z * inLS;
    __hip_bfloat16* outp = out + (size_t)blockIdx.z * outLS;
    int k0 = blockIdx.x * 32, n0 = blockIdx.y * 32;
    int tx = threadIdx.x & 31, ty = threadIdx.x >> 5;
#pragma unroll
    for (int i = 0; i < 32; i += 8) {
        int k = k0 + ty + i, n = n0 + tx;
        t[ty + i][tx] = (n < N) ? inp[(size_t)k * N + n] : 0.f;
    }
    __syncthreads();
#pragma unroll
    for (int i = 0; i < 32; i += 8) {
        int n = n0 + ty + i, k = k0 + tx;
        if (n < N) outp[(size_t)n * K + k] = __float2bfloat16(t[tx][ty + i]);
    }
}

// ---------------- elementwise ----------------

// input proj (1x1 conv over 4 channels) + input LayerNorm -> h fp32 [NTOK,256]
__global__ __launch_bounds__(256) void k_inproj_ln(const float* __restrict__ x,
                                                   const float* __restrict__ w_in,
                                                   const float* __restrict__ b_in,
                                                   const float* __restrict__ g,
                                                   const float* __restrict__ bt,
                                                   float* __restrict__ h) {
    int tok = blockIdx.x;
    int b = tok >> 10, l = tok & 1023;
    int d = threadIdx.x;
    __shared__ float xs[4];
    __shared__ float sbuf[8];
    if (d < 4) xs[d] = x[((size_t)b * 4 + d) * LQ + l];
    __syncthreads();
    float v = b_in[d];
#pragma unroll
    for (int c = 0; c < 4; c++) v = fmaf(xs[c], w_in[d * 4 + c], v);
    float2 mr = block_meanrstd(v, sbuf);
    h[(size_t)tok * 256 + d] = (v - mr.x) * mr.y * g[d] + bt[d];
}

// per-token LayerNorm: hn(bf16) = LN(h)*g+b
__global__ __launch_bounds__(256) void k_ln(const float* __restrict__ h,
                                            const float* __restrict__ g,
                                            const float* __restrict__ bt,
                                            __hip_bfloat16* __restrict__ hn) {
    int tok = blockIdx.x;
    int d = threadIdx.x;
    __shared__ float sbuf[8];
    float v = h[(size_t)tok * 256 + d];
    float2 mr = block_meanrstd(v, sbuf);
    hn[(size_t)tok * 256 + d] = __float2bfloat16((v - mr.x) * mr.y * g[d] + bt[d]);
}

// causal depthwise conv (k=4, left pad 3) + bias + SiLU. xz x-half (bf16) -> xs (bf16)
__global__ __launch_bounds__(256) void k_conv(const __hip_bfloat16* __restrict__ xz,
                                              const float* __restrict__ cw,
                                              const float* __restrict__ cb,
                                              __hip_bfloat16* __restrict__ xs_out) {
    int i = blockIdx.x * 256 + threadIdx.x;   // over NTOK*512
    int d = i & 511;
    int tok = i >> 9;
    int l = tok & 1023;
    int b = tok >> 10;
    float w0 = cw[d * 4 + 0], w1 = cw[d * 4 + 1], w2 = cw[d * 4 + 2], w3 = cw[d * 4 + 3];
    float accv = cb[d];
    const __hip_bfloat16* base = xz + ((size_t)b * 1024) * 1024 + d;
    if (l >= 3) {
        accv = fmaf(__bfloat162float(base[(size_t)(l - 3) * 1024]), w0, accv);
        accv = fmaf(__bfloat162float(base[(size_t)(l - 2) * 1024]), w1, accv);
        accv = fmaf(__bfloat162float(base[(size_t)(l - 1) * 1024]), w2, accv);
        accv = fmaf(__bfloat162float(base[(size_t)l * 1024]),       w3, accv);
    } else {
        if (l >= 2) accv = fmaf(__bfloat162float(base[(size_t)(l - 2) * 1024]), w1, accv);
        if (l >= 1) accv = fmaf(__bfloat162float(base[(size_t)(l - 1) * 1024]), w2, accv);
        accv = fmaf(__bfloat162float(base[(size_t)l * 1024]), w3, accv);
    }
    xs_out[(size_t)tok * 512 + d] = __float2bfloat16(silu_f(accv));
}

// ---------------- MFMA GEMM ----------------
// C[M,N](epi) = A[M,K](bf16,row-major) * Bp (bf16, n-major: Bp[n][k])
// tile 128x128, BK=32, 4 waves each computing 64x64 (4x4 frags of 16x16x32)
// EPI 0: store bf16 to C [.,N]
// EPI 1: col<512 -> dtb(bf16)=softplus(v+bias[col]); 512..527 -> outB f32; 528..543 -> outC f32
// EPI 2: C(f32)[.,256] += v
template <int EPI>
__global__ __launch_bounds__(256) void k_mfma(const __hip_bfloat16* __restrict__ A,
                                              const __hip_bfloat16* __restrict__ Bp,
                                              void* __restrict__ Cv,
                                              const float* __restrict__ bias,
                                              float* __restrict__ outB,
                                              float* __restrict__ outC,
                                              int N, int K) {
    __shared__ short As[4096];   // [128][32] bf16
    __shared__ short Bs[4096];   // [128][32] bf16 (n-major rows)
    const int tid = threadIdx.x;
    const int w = tid >> 6, l = tid & 63;
    const int bm = blockIdx.x * 128, bn = blockIdx.y * 128;
    const int wm = (w >> 1) * 64, wn = (w & 1) * 64;

    float4v acc[4][4];
#pragma unroll
    for (int i = 0; i < 4; i++)
#pragma unroll
        for (int j = 0; j < 4; j++) acc[i][j] = (float4v)0.f;

    const size_t Kb = (size_t)K * 2;   // row bytes
    const char* Ab = (const char*)A + (size_t)bm * Kb;
    const char* Bb = (const char*)Bp + (size_t)bn * Kb;

    const int lrow = l & 15;
    const int lk8 = (l >> 4) * 8;      // element offset of this lane's 8-k block

    for (int k0 = 0; k0 < K; k0 += 32) {
        // stage A and B tiles: 512 16B-chunks each; chunk c -> row c>>2, seg c&3
#pragma unroll
        for (int i = 0; i < 2; i++) {
            int c0 = (w * 2 + i) * 64;
            int c = c0 + l;
            int r = c >> 2, k16 = c & 3;
            size_t goff = (size_t)r * Kb + (size_t)k0 * 2 + k16 * 16;
            gl_lds16(Ab + goff, (char*)As + (size_t)c0 * 16);
            gl_lds16(Bb + goff, (char*)Bs + (size_t)c0 * 16);
        }
        __syncthreads();   // drains vmcnt -> staged data visible

        short8v af[4], bf[4];
#pragma unroll
        for (int mi = 0; mi < 4; mi++)
            af[mi] = *(const short8v*)&As[(wm + mi * 16 + lrow) * 32 + lk8];
#pragma unroll
        for (int ni = 0; ni < 4; ni++)
            bf[ni] = *(const short8v*)&Bs[(wn + ni * 16 + lrow) * 32 + lk8];
#pragma unroll
        for (int mi = 0; mi < 4; mi++)
#pragma unroll
            for (int ni = 0; ni < 4; ni++)
                acc[mi][ni] = __builtin_amdgcn_mfma_f32_16x16x32_bf16(
                    af[mi], bf[ni], acc[mi][ni], 0, 0, 0);
        __syncthreads();   // all consumed before next stage overwrites
    }

    const int lq = (l >> 4) * 4;
#pragma unroll
    for (int mi = 0; mi < 4; mi++) {
#pragma unroll
        for (int ni = 0; ni < 4; ni++) {
            int row0 = bm + wm + mi * 16 + lq;
            int col = bn + wn + ni * 16 + lrow;
            if (EPI == 0) {
                __hip_bfloat16* o = (__hip_bfloat16*)Cv;
#pragma unroll
                for (int r = 0; r < 4; r++)
                    o[(size_t)(row0 + r) * N + col] = __float2bfloat16(acc[mi][ni][r]);
            } else if (EPI == 1) {
                if (col < 512) {
                    __hip_bfloat16* o = (__hip_bfloat16*)Cv;
                    float bc = bias[col];
#pragma unroll
                    for (int r = 0; r < 4; r++)
                        o[(size_t)(row0 + r) * 512 + col] =
                            __float2bfloat16(softplus_f(acc[mi][ni][r] + bc));
                } else if (col < 528) {
#pragma unroll
                    for (int r = 0; r < 4; r++)
                        outB[(size_t)(row0 + r) * 16 + (col - 512)] = acc[mi][ni][r];
                } else if (col < 544) {
#pragma unroll
                    for (int r = 0; r < 4; r++)
                        outC[(size_t)(row0 + r) * 16 + (col - 528)] = acc[mi][ni][r];
                }
            } else {
                float* o = (float*)Cv;
#pragma unroll
                for (int r = 0; r < 4; r++)
                    o[(size_t)(row0 + r) * 256 + col] += acc[mi][ni][r];
            }
        }
    }
}

// ---------------- chunked selective scan ----------------
// thread layout (256 thr): wave = tid>>6, lane = tid&63, s = lane&15,
// d = dg*16 + wave*4 + (lane>>4);  grid: b(8) x chunk(8) x dgroup(32)

// pass 1: local scan (h0 = 0) within each 128-step chunk; y (bf16) local
__global__ __launch_bounds__(256) void k_scan1(const __hip_bfloat16* __restrict__ xs,
                                               const __hip_bfloat16* __restrict__ dt,
                                               const float* __restrict__ Bin,
                                               const float* __restrict__ Cin,
                                               const float* __restrict__ A_log,
                                               __hip_bfloat16* __restrict__ y,
                                               float* __restrict__ h_end,
                                               float* __restrict__ dtsum) {
    int bx = blockIdx.x;
    int dg = bx & 31;
    int c  = (bx >> 5) & 7;
    int b  = bx >> 8;
    int tid = threadIdx.x;
    int lane = tid & 63;
    int wave = tid >> 6;
    int s = lane & 15;
    int d = dg * 16 + wave * 4 + (lane >> 4);

    float Av = -__expf(A_log[d * 16 + s]);
    float h = 0.f, dts = 0.f;

    const size_t tok0 = (size_t)b * 1024 + (size_t)c * CHLEN;
    const __hip_bfloat16* dt_p = dt + tok0 * 512 + d;
    const __hip_bfloat16* x_p  = xs + tok0 * 512 + d;
    const float* B_p  = Bin + tok0 * 16 + s;
    const float* C_p  = Cin + tok0 * 16 + s;
    __hip_bfloat16* y_p = y + tok0 * 512 + d;

    const int U = 4;
    for (int t = 0; t < CHLEN; t += U) {
        float dtv[U], xv[U], bv[U], cv[U];
#pragma unroll
        for (int j = 0; j < U; j++) {
            dtv[j] = __bfloat162float(dt_p[(size_t)(t + j) * 512]);
            xv[j]  = __bfloat162float(x_p[(size_t)(t + j) * 512]);
            bv[j]  = B_p[(size_t)(t + j) * 16];
            cv[j]  = C_p[(size_t)(t + j) * 16];
        }
#pragma unroll
        for (int j = 0; j < U; j++) {
            float a = __expf(Av * dtv[j]);
            h = fmaf(a, h, dtv[j] * xv[j] * bv[j]);
            dts += dtv[j];
            float yp = h * cv[j];
            yp += __shfl_xor(yp, 1);
            yp += __shfl_xor(yp, 2);
            yp += __shfl_xor(yp, 4);
            yp += __shfl_xor(yp, 8);
            if (s == 0) y_p[(size_t)(t + j) * 512] = __float2bfloat16(yp);
        }
    }
    size_t cidx = (size_t)(b * NCHUNK + c) * 512 + d;
    h_end[cidx * 16 + s] = h;
    if (s == 0) dtsum[cidx] = dts;
}

// pass 2: serial carry across 8 chunks per (b,d,s)
__global__ __launch_bounds__(256) void k_carry(const float* __restrict__ h_end,
                                               const float* __restrict__ dtsum,
                                               const float* __restrict__ A_log,
                                               float* __restrict__ H_in) {
    int idx = blockIdx.x * 256 + threadIdx.x;  // 65536 = 8*512*16
    int s = idx & 15;
    int d = (idx >> 4) & 511;
    int b = idx >> 13;
    float Av = -__expf(A_log[d * 16 + s]);
    float H = 0.f;
#pragma unroll
    for (int c = 0; c < NCHUNK; c++) {
        size_t cidx = (size_t)(b * NCHUNK + c) * 512 + d;
        H_in[cidx * 16 + s] = H;
        H = fmaf(__expf(Av * dtsum[cidx]), H, h_end[cidx * 16 + s]);
    }
}

// pass 3: add cross-chunk correction + fused gate, write bf16 (in place on y)
__global__ __launch_bounds__(256) void k_scan2(const __hip_bfloat16* __restrict__ dt,
                                               const float* __restrict__ Cin,
                                               const float* __restrict__ A_log,
                                               const float* __restrict__ H_in,
                                               const __hip_bfloat16* __restrict__ xs,
                                               const __hip_bfloat16* __restrict__ xz,
                                               const float* __restrict__ Dv,
                                               __hip_bfloat16* __restrict__ y) {
    int bx = blockIdx.x;
    int dg = bx & 31;
    int c  = (bx >> 5) & 7;
    int b  = bx >> 8;
    int tid = threadIdx.x;
    int lane = tid & 63;
    int wave = tid >> 6;
    int s = lane & 15;
    int d = dg * 16 + wave * 4 + (lane >> 4);

    float Av = -__expf(A_log[d * 16 + s]);
    size_t cidx = (size_t)(b * NCHUNK + c) * 512 + d;
    float H = H_in[cidx * 16 + s];
    bool haveH = __any(H != 0.f);
    float Dd = Dv[d];

    const size_t tok0 = (size_t)b * 1024 + (size_t)c * CHLEN;
    const __hip_bfloat16* dt_p = dt + tok0 * 512 + d;
    const float* C_p  = Cin + tok0 * 16 + s;
    const __hip_bfloat16* x_p  = xs + tok0 * 512 + d;
    const __hip_bfloat16* z_p  = xz + tok0 * 1024 + 512 + d;
    __hip_bfloat16* y_p = y + tok0 * 512 + d;

    float cumdt = 0.f;
    const int U = 4;
    for (int t = 0; t < CHLEN; t += U) {
        float dtv[U], cv[U];
#pragma unroll
        for (int j = 0; j < U; j++) {
            dtv[j] = __bfloat162float(dt_p[(size_t)(t + j) * 512]);
            cv[j]  = C_p[(size_t)(t + j) * 16];
        }
#pragma unroll
        for (int j = 0; j < U; j++) {
            cumdt += dtv[j];
            float corr = 0.f;
            if (haveH) {
                corr = __expf(Av * cumdt) * H * cv[j];
                corr += __shfl_xor(corr, 1);
                corr += __shfl_xor(corr, 2);
                corr += __shfl_xor(corr, 4);
                corr += __shfl_xor(corr, 8);
            }
            if (s == 0) {
                size_t off = (size_t)(t + j) * 512;
                float xsv = __bfloat162float(x_p[off]);
                float zv  = __bfloat162float(z_p[(size_t)(t + j) * 1024]);
                float yl  = __bfloat162float(y_p[off]);
                y_p[off] = __float2bfloat16((yl + corr + Dd * xsv) * silu_f(zv));
            }
        }
    }
}

// per-token mean/rstd for final LN
__global__ __launch_bounds__(256) void k_stats(const float* __restrict__ h,
                                               float2* __restrict__ stats) {
    int tok = blockIdx.x * 4 + (threadIdx.x >> 6);
    int lane = threadIdx.x & 63;
    float4 v = *(const float4*)&h[(size_t)tok * 256 + lane * 4];
    float sm = v.x + v.y + v.z + v.w;
    float sq = v.x * v.x + v.y * v.y + v.z * v.z + v.w * v.w;
#pragma unroll
    for (int o = 32; o; o >>= 1) {
        sm += __shfl_xor(sm, o);
        sq += __shfl_xor(sq, o);
    }
    if (lane == 0) {
        float m = sm * (1.f / 256.f);
        float var = sq * (1.f / 256.f) - m * m;
        stats[tok] = make_float2(m, rsqrtf(var + 1e-5f));
    }
}

// out[b,d] = mean_l( LN(h)*g+b )
__global__ __launch_bounds__(256) void k_out(const float* __restrict__ h,
                                             const float2* __restrict__ stats,
                                             const float* __restrict__ g,
                                             const float* __restrict__ bias,
                                             float* __restrict__ out) {
    int b = blockIdx.x >> 3;
    int chunk = blockIdx.x & 7;
    int d = threadIdx.x;
    float accv = 0.f;
    for (int l = chunk * 128; l < chunk * 128 + 128; l++) {
        float2 st = stats[b * 1024 + l];
        accv += (h[((size_t)b * 1024 + l) * 256 + d] - st.x) * st.y;
    }
    float res = accv * g[d] * (1.f / 1024.f);
    if (chunk == 0) res += bias[d];
    atomicAdd(&out[b * 256 + d], res);
}

// ---------------- launch ----------------

extern "C" void kernel_launch(void* const* d_in, const int* in_sizes, int n_in,
                              void* d_out, int out_size, void* d_ws, size_t ws_size,
                              hipStream_t stream) {
    const float* x       = (const float*)d_in[0];
    const float* w_in    = (const float*)d_in[1];
    const float* b_in    = (const float*)d_in[2];
    const float* ln_in_g = (const float*)d_in[3];
    const float* ln_in_b = (const float*)d_in[4];
    const float* ln_g    = (const float*)d_in[5];
    const float* ln_b    = (const float*)d_in[6];
    const float* W_inproj= (const float*)d_in[7];
    const float* conv_w  = (const float*)d_in[8];
    const float* conv_b  = (const float*)d_in[9];
    const float* W_dt    = (const float*)d_in[10];
    const float* b_dt    = (const float*)d_in[11];
    const float* W_B     = (const float*)d_in[12];
    const float* W_C     = (const float*)d_in[13];
    const float* A_log   = (const float*)d_in[14];
    const float* Dp      = (const float*)d_in[15];
    const float* W_out   = (const float*)d_in[16];
    const float* ln_f_g  = (const float*)d_in[17];
    const float* ln_f_b  = (const float*)d_in[18];

    float* out = (float*)d_out;

    char* p = (char*)d_ws;
    auto alloc = [&](size_t bytes) { char* r = p; p += (bytes + 255) & ~(size_t)255; return r; };

    float* h            = (float*)alloc((size_t)NTOK * 256 * 4);
    __hip_bfloat16* hn  = (__hip_bfloat16*)alloc((size_t)NTOK * 256 * 2);
    __hip_bfloat16* xz  = (__hip_bfloat16*)alloc((size_t)NTOK * 1024 * 2);
    __hip_bfloat16* xs  = (__hip_bfloat16*)alloc((size_t)NTOK * 512 * 2);
    __hip_bfloat16* dtb = (__hip_bfloat16*)alloc((size_t)NTOK * 512 * 2);
    float* Bin          = (float*)alloc((size_t)NTOK * 16 * 4);
    float* Cin          = (float*)alloc((size_t)NTOK * 16 * 4);
    __hip_bfloat16* yb  = (__hip_bfloat16*)alloc((size_t)NTOK * 512 * 2);
    float2* stats       = (float2*)alloc((size_t)NTOK * 8);
    float* h_end        = (float*)alloc((size_t)BQ * NCHUNK * 512 * 16 * 4);
    float* H_in         = (float*)alloc((size_t)BQ * NCHUNK * 512 * 16 * 4);
    float* dtsum        = (float*)alloc((size_t)BQ * NCHUNK * 512 * 4);
    __hip_bfloat16* W1p = (__hip_bfloat16*)alloc((size_t)NLAYER * 1024 * 256 * 2);
    __hip_bfloat16* W2p = (__hip_bfloat16*)alloc((size_t)NLAYER * 640 * 512 * 2);
    __hip_bfloat16* W3p = (__hip_bfloat16*)alloc((size_t)NLAYER * 256 * 512 * 2);

    hipMemsetAsync(d_out, 0, (size_t)out_size * sizeof(float), stream);
    hipMemsetAsync(W2p, 0, (size_t)NLAYER * 640 * 512 * 2, stream);

    // weight transpose+cast (per layer via grid.z)
    k_tr<<<dim3(8, 32, NLAYER), 256, 0, stream>>>(W_inproj, W1p, 256, 1024, 256 * 1024, 1024 * 256);
    k_tr<<<dim3(16, 16, NLAYER), 256, 0, stream>>>(W_dt, W2p, 512, 512, 512 * 512, 640 * 512);
    k_tr<<<dim3(16, 1, NLAYER), 256, 0, stream>>>(W_B, W2p + (size_t)512 * 512, 512, 16, 512 * 16, 640 * 512);
    k_tr<<<dim3(16, 1, NLAYER), 256, 0, stream>>>(W_C, W2p + (size_t)528 * 512, 512, 16, 512 * 16, 640 * 512);
    k_tr<<<dim3(16, 8, NLAYER), 256, 0, stream>>>(W_out, W3p, 512, 256, 512 * 256, 256 * 512);

    k_inproj_ln<<<NTOK, 256, 0, stream>>>(x, w_in, b_in, ln_in_g, ln_in_b, h);

    for (int l = 0; l < NLAYER; l++) {
        k_ln<<<NTOK, 256, 0, stream>>>(h, ln_g + l * 256, ln_b + l * 256, hn);

        k_mfma<0><<<dim3(64, 8), 256, 0, stream>>>(hn, W1p + (size_t)l * 1024 * 256, xz,
                                                   nullptr, nullptr, nullptr, 1024, 256);

        k_conv<<<(NTOK * 512) / 256, 256, 0, stream>>>(xz, conv_w + (size_t)l * 512 * 4,
                                                       conv_b + (size_t)l * 512, xs);

        k_mfma<1><<<dim3(64, 5), 256, 0, stream>>>(xs, W2p + (size_t)l * 640 * 512, dtb,
                                                   b_dt + (size_t)l * 512, Bin, Cin, 576, 512);

        const float* Al = A_log + (size_t)l * 512 * 16;
        k_scan1<<<2048, 256, 0, stream>>>(xs, dtb, Bin, Cin, Al, yb, h_end, dtsum);
        k_carry<<<256, 256, 0, stream>>>(h_end, dtsum, Al, H_in);
        k_scan2<<<2048, 256, 0, stream>>>(dtb, Cin, Al, H_in, xs, xz, Dp + (size_t)l * 512, yb);

        k_mfma<2><<<dim3(64, 2), 256, 0, stream>>>(yb, W3p + (size_t)l * 256 * 512, h,
                                                   nullptr, nullptr, nullptr, 256, 512);
    }

    k_stats<<<NTOK / 4, 256, 0, stream>>>(h, stats);
    k_out<<<64, 256, 0, stream>>>(h, stats, ln_f_g, ln_f_b, out);
}

// Round 4
// 913.114 us; speedup vs baseline: 2.2627x; 1.2478x over previous
//
#include <hip/hip_runtime.h>
#include <hip/hip_bf16.h>
#include <math.h>

#define BQ 8
#define LQ 1024
#define DMODEL 256
#define DINNER 512
#define DSTATE 16
#define NLAYER 4
#define NTOK (BQ * LQ)          // 8192
#define NCHUNK 16
#define CHLEN 64

typedef __attribute__((ext_vector_type(8))) short short8v;
typedef __attribute__((ext_vector_type(4))) float float4v;

// ---------------- helpers ----------------

__device__ inline float silu_f(float x) { return x / (1.f + __expf(-x)); }

__device__ inline float softplus_f(float x) {
    return (x > 20.f) ? x : log1pf(expf(x));
}

__device__ __forceinline__ void gl_lds16(const void* g, void* l) {
    __builtin_amdgcn_global_load_lds(
        (const __attribute__((address_space(1))) unsigned int*)g,
        (__attribute__((address_space(3))) unsigned int*)l,
        16, 0, 0);
}

// block-wide mean / rstd over 256 values (one per thread)
__device__ inline float2 block_meanrstd(float v, float* sbuf) {
    float sm = v, sq = v * v;
#pragma unroll
    for (int o = 32; o; o >>= 1) {
        sm += __shfl_xor(sm, o);
        sq += __shfl_xor(sq, o);
    }
    int w = threadIdx.x >> 6;
    if ((threadIdx.x & 63) == 0) { sbuf[w] = sm; sbuf[4 + w] = sq; }
    __syncthreads();
    sm = sbuf[0] + sbuf[1] + sbuf[2] + sbuf[3];
    sq = sbuf[4] + sbuf[5] + sbuf[6] + sbuf[7];
    float m = sm * (1.f / 256.f);
    float var = sq * (1.f / 256.f) - m * m;
    return make_float2(m, rsqrtf(var + 1e-5f));
}

// ---------------- weight prep ----------------

// transpose+cast: in [z][K][N] fp32 -> out [z][N][K] bf16
__global__ __launch_bounds__(256) void k_tr(const float* __restrict__ in,
                                            __hip_bfloat16* __restrict__ out,
                                            int K, int N, int inLS, int outLS) {
    __shared__ float t[32][33];
    const float* inp = in + (size_t)blockIdx.z * inLS;
    __hip_bfloat16* outp = out + (size_t)blockIdx.z * outLS;
    int k0 = blockIdx.x * 32, n0 = blockIdx.y * 32;
    int tx = threadIdx.x & 31, ty = threadIdx.x >> 5;
#pragma unroll
    for (int i = 0; i < 32; i += 8) {
        int k = k0 + ty + i, n = n0 + tx;
        t[ty + i][tx] = (n < N) ? inp[(size_t)k * N + n] : 0.f;
    }
    __syncthreads();
#pragma unroll
    for (int i = 0; i < 32; i += 8) {
        int n = n0 + ty + i, k = k0 + tx;
        if (n < N) outp[(size_t)n * K + k] = __float2bfloat16(t[tx][ty + i]);
    }
}

// ---------------- elementwise ----------------

__global__ __launch_bounds__(256) void k_inproj_ln(const float* __restrict__ x,
                                                   const float* __restrict__ w_in,
                                                   const float* __restrict__ b_in,
                                                   const float* __restrict__ g,
                                                   const float* __restrict__ bt,
                                                   float* __restrict__ h) {
    int tok = blockIdx.x;
    int b = tok >> 10, l = tok & 1023;
    int d = threadIdx.x;
    __shared__ float xs[4];
    __shared__ float sbuf[8];
    if (d < 4) xs[d] = x[((size_t)b * 4 + d) * LQ + l];
    __syncthreads();
    float v = b_in[d];
#pragma unroll
    for (int c = 0; c < 4; c++) v = fmaf(xs[c], w_in[d * 4 + c], v);
    float2 mr = block_meanrstd(v, sbuf);
    h[(size_t)tok * 256 + d] = (v - mr.x) * mr.y * g[d] + bt[d];
}

__global__ __launch_bounds__(256) void k_ln(const float* __restrict__ h,
                                            const float* __restrict__ g,
                                            const float* __restrict__ bt,
                                            __hip_bfloat16* __restrict__ hn) {
    int tok = blockIdx.x;
    int d = threadIdx.x;
    __shared__ float sbuf[8];
    float v = h[(size_t)tok * 256 + d];
    float2 mr = block_meanrstd(v, sbuf);
    hn[(size_t)tok * 256 + d] = __float2bfloat16((v - mr.x) * mr.y * g[d] + bt[d]);
}

__global__ __launch_bounds__(256) void k_conv(const __hip_bfloat16* __restrict__ xz,
                                              const float* __restrict__ cw,
                                              const float* __restrict__ cb,
                                              __hip_bfloat16* __restrict__ xs_out) {
    int i = blockIdx.x * 256 + threadIdx.x;   // over NTOK*512
    int d = i & 511;
    int tok = i >> 9;
    int l = tok & 1023;
    int b = tok >> 10;
    float w0 = cw[d * 4 + 0], w1 = cw[d * 4 + 1], w2 = cw[d * 4 + 2], w3 = cw[d * 4 + 3];
    float accv = cb[d];
    const __hip_bfloat16* base = xz + ((size_t)b * 1024) * 1024 + d;
    if (l >= 3) {
        accv = fmaf(__bfloat162float(base[(size_t)(l - 3) * 1024]), w0, accv);
        accv = fmaf(__bfloat162float(base[(size_t)(l - 2) * 1024]), w1, accv);
        accv = fmaf(__bfloat162float(base[(size_t)(l - 1) * 1024]), w2, accv);
        accv = fmaf(__bfloat162float(base[(size_t)l * 1024]),       w3, accv);
    } else {
        if (l >= 2) accv = fmaf(__bfloat162float(base[(size_t)(l - 2) * 1024]), w1, accv);
        if (l >= 1) accv = fmaf(__bfloat162float(base[(size_t)(l - 1) * 1024]), w2, accv);
        accv = fmaf(__bfloat162float(base[(size_t)l * 1024]), w3, accv);
    }
    xs_out[(size_t)tok * 512 + d] = __float2bfloat16(silu_f(accv));
}

// ---------------- MFMA GEMM ----------------
template <int EPI>
__global__ __launch_bounds__(256) void k_mfma(const __hip_bfloat16* __restrict__ A,
                                              const __hip_bfloat16* __restrict__ Bp,
                                              void* __restrict__ Cv,
                                              const float* __restrict__ bias,
                                              float* __restrict__ outB,
                                              float* __restrict__ outC,
                                              int N, int K) {
    __shared__ short As[4096];   // [128][32] bf16
    __shared__ short Bs[4096];   // [128][32] bf16 (n-major rows)
    const int tid = threadIdx.x;
    const int w = tid >> 6, l = tid & 63;
    const int bm = blockIdx.x * 128, bn = blockIdx.y * 128;
    const int wm = (w >> 1) * 64, wn = (w & 1) * 64;

    float4v acc[4][4];
#pragma unroll
    for (int i = 0; i < 4; i++)
#pragma unroll
        for (int j = 0; j < 4; j++) acc[i][j] = (float4v)0.f;

    const size_t Kb = (size_t)K * 2;
    const char* Ab = (const char*)A + (size_t)bm * Kb;
    const char* Bb = (const char*)Bp + (size_t)bn * Kb;

    const int lrow = l & 15;
    const int lk8 = (l >> 4) * 8;

    for (int k0 = 0; k0 < K; k0 += 32) {
#pragma unroll
        for (int i = 0; i < 2; i++) {
            int c0 = (w * 2 + i) * 64;
            int c = c0 + l;
            int r = c >> 2, k16 = c & 3;
            size_t goff = (size_t)r * Kb + (size_t)k0 * 2 + k16 * 16;
            gl_lds16(Ab + goff, (char*)As + (size_t)c0 * 16);
            gl_lds16(Bb + goff, (char*)Bs + (size_t)c0 * 16);
        }
        __syncthreads();

        short8v af[4], bf[4];
#pragma unroll
        for (int mi = 0; mi < 4; mi++)
            af[mi] = *(const short8v*)&As[(wm + mi * 16 + lrow) * 32 + lk8];
#pragma unroll
        for (int ni = 0; ni < 4; ni++)
            bf[ni] = *(const short8v*)&Bs[(wn + ni * 16 + lrow) * 32 + lk8];
#pragma unroll
        for (int mi = 0; mi < 4; mi++)
#pragma unroll
            for (int ni = 0; ni < 4; ni++)
                acc[mi][ni] = __builtin_amdgcn_mfma_f32_16x16x32_bf16(
                    af[mi], bf[ni], acc[mi][ni], 0, 0, 0);
        __syncthreads();
    }

    const int lq = (l >> 4) * 4;
#pragma unroll
    for (int mi = 0; mi < 4; mi++) {
#pragma unroll
        for (int ni = 0; ni < 4; ni++) {
            int row0 = bm + wm + mi * 16 + lq;
            int col = bn + wn + ni * 16 + lrow;
            if (EPI == 0) {
                __hip_bfloat16* o = (__hip_bfloat16*)Cv;
#pragma unroll
                for (int r = 0; r < 4; r++)
                    o[(size_t)(row0 + r) * N + col] = __float2bfloat16(acc[mi][ni][r]);
            } else if (EPI == 1) {
                if (col < 512) {
                    __hip_bfloat16* o = (__hip_bfloat16*)Cv;
                    float bc = bias[col];
#pragma unroll
                    for (int r = 0; r < 4; r++)
                        o[(size_t)(row0 + r) * 512 + col] =
                            __float2bfloat16(softplus_f(acc[mi][ni][r] + bc));
                } else if (col < 528) {
#pragma unroll
                    for (int r = 0; r < 4; r++)
                        outB[(size_t)(row0 + r) * 16 + (col - 512)] = acc[mi][ni][r];
                } else if (col < 544) {
#pragma unroll
                    for (int r = 0; r < 4; r++)
                        outC[(size_t)(row0 + r) * 16 + (col - 528)] = acc[mi][ni][r];
                }
            } else {
                float* o = (float*)Cv;
#pragma unroll
                for (int r = 0; r < 4; r++)
                    o[(size_t)(row0 + r) * 256 + col] += acc[mi][ni][r];
            }
        }
    }
}

// ---------------- chunked selective scan (register-state form) ----------------
// grid: 1024 blocks = dtile(8) x chunk(16) x b(8); block = 256 threads.

// pass A: per-chunk local scan (h0=0), outputs h_end[b,c,d,s] and dtsum[b,c,d].
// layout: wave = state-group sg (4 states), lane = d (64 consecutive) -> coalesced dt/x.
__global__ __launch_bounds__(256) void k_scanA(const __hip_bfloat16* __restrict__ xs,
                                               const __hip_bfloat16* __restrict__ dt,
                                               const float* __restrict__ Bin,
                                               const float* __restrict__ A_log,
                                               float* __restrict__ h_end,
                                               float* __restrict__ dtsum) {
    int bx = blockIdx.x;
    int dtile = bx & 7;
    int c = (bx >> 3) & 15;
    int b = bx >> 7;
    int lane = threadIdx.x & 63, wave = threadIdx.x >> 6;
    int d = dtile * 64 + lane;
    int s0 = wave * 4;

    float4 Ar = *(const float4*)&A_log[d * 16 + s0];
    float A0 = -__expf(Ar.x), A1 = -__expf(Ar.y), A2 = -__expf(Ar.z), A3 = -__expf(Ar.w);

    const size_t tok0 = (size_t)b * LQ + (size_t)c * CHLEN;
    const __hip_bfloat16* dt_p = dt + tok0 * 512 + d;
    const __hip_bfloat16* x_p  = xs + tok0 * 512 + d;
    const float* B_p = Bin + tok0 * 16 + s0;

    float h0 = 0.f, h1 = 0.f, h2 = 0.f, h3 = 0.f, dts = 0.f;

    const int U = 4;
    float dtA[U], xA[U]; float4 BA[U];
    float dtB[U], xB[U]; float4 BB[U];

    auto loadA = [&](int t0) {
#pragma unroll
        for (int j = 0; j < U; j++) {
            dtA[j] = __bfloat162float(dt_p[(size_t)(t0 + j) * 512]);
            xA[j]  = __bfloat162float(x_p[(size_t)(t0 + j) * 512]);
            BA[j]  = *(const float4*)&B_p[(size_t)(t0 + j) * 16];
        }
    };
    auto loadB = [&](int t0) {
#pragma unroll
        for (int j = 0; j < U; j++) {
            dtB[j] = __bfloat162float(dt_p[(size_t)(t0 + j) * 512]);
            xB[j]  = __bfloat162float(x_p[(size_t)(t0 + j) * 512]);
            BB[j]  = *(const float4*)&B_p[(size_t)(t0 + j) * 16];
        }
    };
    auto compA = [&]() {
#pragma unroll
        for (int j = 0; j < U; j++) {
            float dtv = dtA[j], u = dtv * xA[j];
            dts += dtv;
            h0 = fmaf(__expf(A0 * dtv), h0, u * BA[j].x);
            h1 = fmaf(__expf(A1 * dtv), h1, u * BA[j].y);
            h2 = fmaf(__expf(A2 * dtv), h2, u * BA[j].z);
            h3 = fmaf(__expf(A3 * dtv), h3, u * BA[j].w);
        }
    };
    auto compB = [&]() {
#pragma unroll
        for (int j = 0; j < U; j++) {
            float dtv = dtB[j], u = dtv * xB[j];
            dts += dtv;
            h0 = fmaf(__expf(A0 * dtv), h0, u * BB[j].x);
            h1 = fmaf(__expf(A1 * dtv), h1, u * BB[j].y);
            h2 = fmaf(__expf(A2 * dtv), h2, u * BB[j].z);
            h3 = fmaf(__expf(A3 * dtv), h3, u * BB[j].w);
        }
    };

    loadA(0);
    for (int t = 0; t < CHLEN; t += 2 * U) {
        loadB(t + U);
        compA();
        if (t + 2 * U < CHLEN) loadA(t + 2 * U);
        compB();
    }

    size_t cidx = (size_t)(b * NCHUNK + c) * 512 + d;
    *(float4*)&h_end[cidx * 16 + s0] = make_float4(h0, h1, h2, h3);
    if (wave == 0) dtsum[cidx] = dts;
}

// pass B: serial carry across 16 chunks per (b,d,s)
__global__ __launch_bounds__(256) void k_carry(const float* __restrict__ h_end,
                                               const float* __restrict__ dtsum,
                                               const float* __restrict__ A_log,
                                               float* __restrict__ H_in) {
    int idx = blockIdx.x * 256 + threadIdx.x;  // 65536 = 8*512*16
    int s = idx & 15;
    int d = (idx >> 4) & 511;
    int b = idx >> 13;
    float Av = -__expf(A_log[d * 16 + s]);
    float H = 0.f;
#pragma unroll
    for (int c = 0; c < NCHUNK; c++) {
        size_t cidx = (size_t)(b * NCHUNK + c) * 512 + d;
        H_in[cidx * 16 + s] = H;
        H = fmaf(__expf(Av * dtsum[cidx]), H, h_end[cidx * 16 + s]);
    }
}

// pass C: re-run recurrence with correct H_in, compute y + fused gate.
// layout: lane = dl*4+sg (16 d x 4 sg per wave); 2-shfl reduce over sg.
__global__ __launch_bounds__(256) void k_scanC(const __hip_bfloat16* __restrict__ xs,
                                               const __hip_bfloat16* __restrict__ dt,
                                               const float* __restrict__ Bin,
                                               const float* __restrict__ Cin,
                                               const float* __restrict__ A_log,
                                               const float* __restrict__ H_in,
                                               const __hip_bfloat16* __restrict__ xz,
                                               const float* __restrict__ Dv,
                                               __hip_bfloat16* __restrict__ y) {
    int bx = blockIdx.x;
    int dtile = bx & 7;
    int c = (bx >> 3) & 15;
    int b = bx >> 7;
    int lane = threadIdx.x & 63, wave = threadIdx.x >> 6;
    int sg = lane & 3, dl = lane >> 2;
    int d = dtile * 64 + wave * 16 + dl;
    int s0 = sg * 4;

    float4 Ar = *(const float4*)&A_log[d * 16 + s0];
    float A0 = -__expf(Ar.x), A1 = -__expf(Ar.y), A2 = -__expf(Ar.z), A3 = -__expf(Ar.w);

    size_t cidx = (size_t)(b * NCHUNK + c) * 512 + d;
    float4 Hv = *(const float4*)&H_in[cidx * 16 + s0];
    float h0 = Hv.x, h1 = Hv.y, h2 = Hv.z, h3 = Hv.w;
    float Dd = Dv[d];

    const size_t tok0 = (size_t)b * LQ + (size_t)c * CHLEN;
    const __hip_bfloat16* dt_p = dt + tok0 * 512 + d;
    const __hip_bfloat16* x_p  = xs + tok0 * 512 + d;
    const __hip_bfloat16* z_p  = xz + tok0 * 1024 + 512 + d;
    const float* B_p = Bin + tok0 * 16 + s0;
    const float* C_p = Cin + tok0 * 16 + s0;
    __hip_bfloat16* y_p = y + tok0 * 512 + d;

    const int U = 4;
    float dtA[U], xA[U], zA[U]; float4 BA[U], CA[U];
    float dtB[U], xB[U], zB[U]; float4 BB[U], CB[U];

    auto loadA = [&](int t0) {
#pragma unroll
        for (int j = 0; j < U; j++) {
            dtA[j] = __bfloat162float(dt_p[(size_t)(t0 + j) * 512]);
            xA[j]  = __bfloat162float(x_p[(size_t)(t0 + j) * 512]);
            zA[j]  = __bfloat162float(z_p[(size_t)(t0 + j) * 1024]);
            BA[j]  = *(const float4*)&B_p[(size_t)(t0 + j) * 16];
            CA[j]  = *(const float4*)&C_p[(size_t)(t0 + j) * 16];
        }
    };
    auto loadB = [&](int t0) {
#pragma unroll
        for (int j = 0; j < U; j++) {
            dtB[j] = __bfloat162float(dt_p[(size_t)(t0 + j) * 512]);
            xB[j]  = __bfloat162float(x_p[(size_t)(t0 + j) * 512]);
            zB[j]  = __bfloat162float(z_p[(size_t)(t0 + j) * 1024]);
            BB[j]  = *(const float4*)&B_p[(size_t)(t0 + j) * 16];
            CB[j]  = *(const float4*)&C_p[(size_t)(t0 + j) * 16];
        }
    };
    auto compA = [&](int t0) {
#pragma unroll
        for (int j = 0; j < U; j++) {
            float dtv = dtA[j], u = dtv * xA[j];
            h0 = fmaf(__expf(A0 * dtv), h0, u * BA[j].x);
            h1 = fmaf(__expf(A1 * dtv), h1, u * BA[j].y);
            h2 = fmaf(__expf(A2 * dtv), h2, u * BA[j].z);
            h3 = fmaf(__expf(A3 * dtv), h3, u * BA[j].w);
            float yp = h0 * CA[j].x + h1 * CA[j].y + h2 * CA[j].z + h3 * CA[j].w;
            yp += __shfl_xor(yp, 1);
            yp += __shfl_xor(yp, 2);
            if (sg == 0)
                y_p[(size_t)(t0 + j) * 512] =
                    __float2bfloat16((yp + Dd * xA[j]) * silu_f(zA[j]));
        }
    };
    auto compB = [&](int t0) {
#pragma unroll
        for (int j = 0; j < U; j++) {
            float dtv = dtB[j], u = dtv * xB[j];
            h0 = fmaf(__expf(A0 * dtv), h0, u * BB[j].x);
            h1 = fmaf(__expf(A1 * dtv), h1, u * BB[j].y);
            h2 = fmaf(__expf(A2 * dtv), h2, u * BB[j].z);
            h3 = fmaf(__expf(A3 * dtv), h3, u * BB[j].w);
            float yp = h0 * CB[j].x + h1 * CB[j].y + h2 * CB[j].z + h3 * CB[j].w;
            yp += __shfl_xor(yp, 1);
            yp += __shfl_xor(yp, 2);
            if (sg == 0)
                y_p[(size_t)(t0 + j) * 512] =
                    __float2bfloat16((yp + Dd * xB[j]) * silu_f(zB[j]));
        }
    };

    loadA(0);
    for (int t = 0; t < CHLEN; t += 2 * U) {
        loadB(t + U);
        compA(t);
        if (t + 2 * U < CHLEN) loadA(t + 2 * U);
        compB(t + U);
    }
}

// per-token mean/rstd for final LN
__global__ __launch_bounds__(256) void k_stats(const float* __restrict__ h,
                                               float2* __restrict__ stats) {
    int tok = blockIdx.x * 4 + (threadIdx.x >> 6);
    int lane = threadIdx.x & 63;
    float4 v = *(const float4*)&h[(size_t)tok * 256 + lane * 4];
    float sm = v.x + v.y + v.z + v.w;
    float sq = v.x * v.x + v.y * v.y + v.z * v.z + v.w * v.w;
#pragma unroll
    for (int o = 32; o; o >>= 1) {
        sm += __shfl_xor(sm, o);
        sq += __shfl_xor(sq, o);
    }
    if (lane == 0) {
        float m = sm * (1.f / 256.f);
        float var = sq * (1.f / 256.f) - m * m;
        stats[tok] = make_float2(m, rsqrtf(var + 1e-5f));
    }
}

__global__ __launch_bounds__(256) void k_out(const float* __restrict__ h,
                                             const float2* __restrict__ stats,
                                             const float* __restrict__ g,
                                             const float* __restrict__ bias,
                                             float* __restrict__ out) {
    int b = blockIdx.x >> 3;
    int chunk = blockIdx.x & 7;
    int d = threadIdx.x;
    float accv = 0.f;
    for (int l = chunk * 128; l < chunk * 128 + 128; l++) {
        float2 st = stats[b * 1024 + l];
        accv += (h[((size_t)b * 1024 + l) * 256 + d] - st.x) * st.y;
    }
    float res = accv * g[d] * (1.f / 1024.f);
    if (chunk == 0) res += bias[d];
    atomicAdd(&out[b * 256 + d], res);
}

// ---------------- launch ----------------

extern "C" void kernel_launch(void* const* d_in, const int* in_sizes, int n_in,
                              void* d_out, int out_size, void* d_ws, size_t ws_size,
                              hipStream_t stream) {
    const float* x       = (const float*)d_in[0];
    const float* w_in    = (const float*)d_in[1];
    const float* b_in    = (const float*)d_in[2];
    const float* ln_in_g = (const float*)d_in[3];
    const float* ln_in_b = (const float*)d_in[4];
    const float* ln_g    = (const float*)d_in[5];
    const float* ln_b    = (const float*)d_in[6];
    const float* W_inproj= (const float*)d_in[7];
    const float* conv_w  = (const float*)d_in[8];
    const float* conv_b  = (const float*)d_in[9];
    const float* W_dt    = (const float*)d_in[10];
    const float* b_dt    = (const float*)d_in[11];
    const float* W_B     = (const float*)d_in[12];
    const float* W_C     = (const float*)d_in[13];
    const float* A_log   = (const float*)d_in[14];
    const float* Dp      = (const float*)d_in[15];
    const float* W_out   = (const float*)d_in[16];
    const float* ln_f_g  = (const float*)d_in[17];
    const float* ln_f_b  = (const float*)d_in[18];

    float* out = (float*)d_out;

    char* p = (char*)d_ws;
    auto alloc = [&](size_t bytes) { char* r = p; p += (bytes + 255) & ~(size_t)255; return r; };

    float* h            = (float*)alloc((size_t)NTOK * 256 * 4);
    __hip_bfloat16* hn  = (__hip_bfloat16*)alloc((size_t)NTOK * 256 * 2);
    __hip_bfloat16* xz  = (__hip_bfloat16*)alloc((size_t)NTOK * 1024 * 2);
    __hip_bfloat16* xs  = (__hip_bfloat16*)alloc((size_t)NTOK * 512 * 2);
    __hip_bfloat16* dtb = (__hip_bfloat16*)alloc((size_t)NTOK * 512 * 2);
    float* Bin          = (float*)alloc((size_t)NTOK * 16 * 4);
    float* Cin          = (float*)alloc((size_t)NTOK * 16 * 4);
    __hip_bfloat16* yb  = (__hip_bfloat16*)alloc((size_t)NTOK * 512 * 2);
    float2* stats       = (float2*)alloc((size_t)NTOK * 8);
    float* h_end        = (float*)alloc((size_t)BQ * NCHUNK * 512 * 16 * 4);
    float* H_in         = (float*)alloc((size_t)BQ * NCHUNK * 512 * 16 * 4);
    float* dtsum        = (float*)alloc((size_t)BQ * NCHUNK * 512 * 4);
    __hip_bfloat16* W1p = (__hip_bfloat16*)alloc((size_t)NLAYER * 1024 * 256 * 2);
    __hip_bfloat16* W2p = (__hip_bfloat16*)alloc((size_t)NLAYER * 640 * 512 * 2);
    __hip_bfloat16* W3p = (__hip_bfloat16*)alloc((size_t)NLAYER * 256 * 512 * 2);

    hipMemsetAsync(d_out, 0, (size_t)out_size * sizeof(float), stream);
    hipMemsetAsync(W2p, 0, (size_t)NLAYER * 640 * 512 * 2, stream);

    k_tr<<<dim3(8, 32, NLAYER), 256, 0, stream>>>(W_inproj, W1p, 256, 1024, 256 * 1024, 1024 * 256);
    k_tr<<<dim3(16, 16, NLAYER), 256, 0, stream>>>(W_dt, W2p, 512, 512, 512 * 512, 640 * 512);
    k_tr<<<dim3(16, 1, NLAYER), 256, 0, stream>>>(W_B, W2p + (size_t)512 * 512, 512, 16, 512 * 16, 640 * 512);
    k_tr<<<dim3(16, 1, NLAYER), 256, 0, stream>>>(W_C, W2p + (size_t)528 * 512, 512, 16, 512 * 16, 640 * 512);
    k_tr<<<dim3(16, 8, NLAYER), 256, 0, stream>>>(W_out, W3p, 512, 256, 512 * 256, 256 * 512);

    k_inproj_ln<<<NTOK, 256, 0, stream>>>(x, w_in, b_in, ln_in_g, ln_in_b, h);

    for (int l = 0; l < NLAYER; l++) {
        k_ln<<<NTOK, 256, 0, stream>>>(h, ln_g + l * 256, ln_b + l * 256, hn);

        k_mfma<0><<<dim3(64, 8), 256, 0, stream>>>(hn, W1p + (size_t)l * 1024 * 256, xz,
                                                   nullptr, nullptr, nullptr, 1024, 256);

        k_conv<<<(NTOK * 512) / 256, 256, 0, stream>>>(xz, conv_w + (size_t)l * 512 * 4,
                                                       conv_b + (size_t)l * 512, xs);

        k_mfma<1><<<dim3(64, 5), 256, 0, stream>>>(xs, W2p + (size_t)l * 640 * 512, dtb,
                                                   b_dt + (size_t)l * 512, Bin, Cin, 576, 512);

        const float* Al = A_log + (size_t)l * 512 * 16;
        k_scanA<<<1024, 256, 0, stream>>>(xs, dtb, Bin, Al, h_end, dtsum);
        k_carry<<<256, 256, 0, stream>>>(h_end, dtsum, Al, H_in);
        k_scanC<<<1024, 256, 0, stream>>>(xs, dtb, Bin, Cin, Al, H_in, xz,
                                          Dp + (size_t)l * 512, yb);

        k_mfma<2><<<dim3(64, 2), 256, 0, stream>>>(yb, W3p + (size_t)l * 256 * 512, h,
                                                   nullptr, nullptr, nullptr, 256, 512);
    }

    k_stats<<<NTOK / 4, 256, 0, stream>>>(h, stats);
    k_out<<<64, 256, 0, stream>>>(h, stats, ln_f_g, ln_f_b, out);
}

// Round 5
// 619.619 us; speedup vs baseline: 3.3345x; 1.4737x over previous
//
#include <hip/hip_runtime.h>
#include <hip/hip_bf16.h>
#include <math.h>

#define BQ 8
#define LQ 1024
#define DMODEL 256
#define DINNER 512
#define DSTATE 16
#define NLAYER 4
#define NTOK (BQ * LQ)          // 8192
#define NCHUNK 16
#define CHLEN 64

typedef __attribute__((ext_vector_type(8))) short short8v;
typedef __attribute__((ext_vector_type(4))) float float4v;

// ---------------- helpers ----------------

__device__ inline float silu_f(float x) { return x / (1.f + __expf(-x)); }

__device__ inline float softplus_f(float x) {
    return (x > 20.f) ? x : log1pf(expf(x));
}

__device__ __forceinline__ void gl_lds16(const void* g, void* l) {
    __builtin_amdgcn_global_load_lds(
        (const __attribute__((address_space(1))) unsigned int*)g,
        (__attribute__((address_space(3))) unsigned int*)l,
        16, 0, 0);
}

// block-wide mean / rstd over 256 values (one per thread)
__device__ inline float2 block_meanrstd(float v, float* sbuf) {
    float sm = v, sq = v * v;
#pragma unroll
    for (int o = 32; o; o >>= 1) {
        sm += __shfl_xor(sm, o);
        sq += __shfl_xor(sq, o);
    }
    int w = threadIdx.x >> 6;
    if ((threadIdx.x & 63) == 0) { sbuf[w] = sm; sbuf[4 + w] = sq; }
    __syncthreads();
    sm = sbuf[0] + sbuf[1] + sbuf[2] + sbuf[3];
    sq = sbuf[4] + sbuf[5] + sbuf[6] + sbuf[7];
    float m = sm * (1.f / 256.f);
    float var = sq * (1.f / 256.f) - m * m;
    return make_float2(m, rsqrtf(var + 1e-5f));
}

// ---------------- weight prep ----------------

// transpose+cast: in [z][K][N] fp32 -> out [z][N][K] bf16
__global__ __launch_bounds__(256) void k_tr(const float* __restrict__ in,
                                            __hip_bfloat16* __restrict__ out,
                                            int K, int N, int inLS, int outLS) {
    __shared__ float t[32][33];
    const float* inp = in + (size_t)blockIdx.z * inLS;
    __hip_bfloat16* outp = out + (size_t)blockIdx.z * outLS;
    int k0 = blockIdx.x * 32, n0 = blockIdx.y * 32;
    int tx = threadIdx.x & 31, ty = threadIdx.x >> 5;
#pragma unroll
    for (int i = 0; i < 32; i += 8) {
        int k = k0 + ty + i, n = n0 + tx;
        t[ty + i][tx] = (n < N) ? inp[(size_t)k * N + n] : 0.f;
    }
    __syncthreads();
#pragma unroll
    for (int i = 0; i < 32; i += 8) {
        int n = n0 + ty + i, k = k0 + tx;
        if (n < N) outp[(size_t)n * K + k] = __float2bfloat16(t[tx][ty + i]);
    }
}

// ---------------- elementwise ----------------

__global__ __launch_bounds__(256) void k_inproj_ln(const float* __restrict__ x,
                                                   const float* __restrict__ w_in,
                                                   const float* __restrict__ b_in,
                                                   const float* __restrict__ g,
                                                   const float* __restrict__ bt,
                                                   float* __restrict__ h) {
    int tok = blockIdx.x;
    int b = tok >> 10, l = tok & 1023;
    int d = threadIdx.x;
    __shared__ float xs[4];
    __shared__ float sbuf[8];
    if (d < 4) xs[d] = x[((size_t)b * 4 + d) * LQ + l];
    __syncthreads();
    float v = b_in[d];
#pragma unroll
    for (int c = 0; c < 4; c++) v = fmaf(xs[c], w_in[d * 4 + c], v);
    float2 mr = block_meanrstd(v, sbuf);
    h[(size_t)tok * 256 + d] = (v - mr.x) * mr.y * g[d] + bt[d];
}

__global__ __launch_bounds__(256) void k_ln(const float* __restrict__ h,
                                            const float* __restrict__ g,
                                            const float* __restrict__ bt,
                                            __hip_bfloat16* __restrict__ hn) {
    int tok = blockIdx.x;
    int d = threadIdx.x;
    __shared__ float sbuf[8];
    float v = h[(size_t)tok * 256 + d];
    float2 mr = block_meanrstd(v, sbuf);
    hn[(size_t)tok * 256 + d] = __float2bfloat16((v - mr.x) * mr.y * g[d] + bt[d]);
}

__global__ __launch_bounds__(256) void k_conv(const __hip_bfloat16* __restrict__ xz,
                                              const float* __restrict__ cw,
                                              const float* __restrict__ cb,
                                              __hip_bfloat16* __restrict__ xs_out) {
    int i = blockIdx.x * 256 + threadIdx.x;   // over NTOK*512
    int d = i & 511;
    int tok = i >> 9;
    int l = tok & 1023;
    int b = tok >> 10;
    float w0 = cw[d * 4 + 0], w1 = cw[d * 4 + 1], w2 = cw[d * 4 + 2], w3 = cw[d * 4 + 3];
    float accv = cb[d];
    const __hip_bfloat16* base = xz + ((size_t)b * 1024) * 1024 + d;
    if (l >= 3) {
        accv = fmaf(__bfloat162float(base[(size_t)(l - 3) * 1024]), w0, accv);
        accv = fmaf(__bfloat162float(base[(size_t)(l - 2) * 1024]), w1, accv);
        accv = fmaf(__bfloat162float(base[(size_t)(l - 1) * 1024]), w2, accv);
        accv = fmaf(__bfloat162float(base[(size_t)l * 1024]),       w3, accv);
    } else {
        if (l >= 2) accv = fmaf(__bfloat162float(base[(size_t)(l - 2) * 1024]), w1, accv);
        if (l >= 1) accv = fmaf(__bfloat162float(base[(size_t)(l - 1) * 1024]), w2, accv);
        accv = fmaf(__bfloat162float(base[(size_t)l * 1024]), w3, accv);
    }
    xs_out[(size_t)tok * 512 + d] = __float2bfloat16(silu_f(accv));
}

// ---------------- MFMA GEMM (double-buffered, BM x 64 tile) ----------------
// C[M,N](epi) = A[M,K](bf16,row-major) * Bp (bf16, n-major: Bp[n][k])
// 4 waves in 2x2: wave covers (BM/2) x 32. BK=32.
// Schedule: stage(buf^1, k+1) issued BEFORE compute(buf) -> loads in flight
// under ds_read+MFMA; one barrier per iteration drains prefetch + guards reuse.
template <int EPI, int BM>
__global__ __launch_bounds__(256) void k_mfma(const __hip_bfloat16* __restrict__ A,
                                              const __hip_bfloat16* __restrict__ Bp,
                                              void* __restrict__ Cv,
                                              const float* __restrict__ bias,
                                              float* __restrict__ outB,
                                              float* __restrict__ outC,
                                              int N, int K) {
    constexpr int BN = 64, BK = 32;
    constexpr int FM = BM / 32;               // M-frags per wave
    constexpr int GA = BM / 16;               // 64-chunk staging groups in A
    constexpr int GB = BN / 16;               // ... in B
    constexpr int PW = (GA + GB) / 4;         // groups per wave

    __shared__ short As[2][BM * BK];
    __shared__ short Bs[2][BN * BK];
    const int tid = threadIdx.x;
    const int w = tid >> 6, l = tid & 63;
    const int bm = blockIdx.x * BM, bn = blockIdx.y * BN;
    const int wm = (w >> 1) * (BM / 2), wn = (w & 1) * 32;

    float4v acc[FM][2];
#pragma unroll
    for (int i = 0; i < FM; i++)
#pragma unroll
        for (int j = 0; j < 2; j++) acc[i][j] = (float4v)0.f;

    const size_t Kb = (size_t)K * 2;
    const char* Ab = (const char*)A + (size_t)bm * Kb;
    const char* Bb = (const char*)Bp + (size_t)bn * Kb;
    const int lrow = l & 15;
    const int lk8 = (l >> 4) * 8;

    auto stage = [&](int buf, int k0) {
#pragma unroll
        for (int gi = 0; gi < PW; gi++) {
            int g = w * PW + gi;
            if (g < GA) {
                int c = g * 64 + l;
                gl_lds16(Ab + (size_t)(c >> 2) * Kb + (size_t)k0 * 2 + (c & 3) * 16,
                         (char*)&As[buf][0] + g * 1024);
            } else {
                int gg = g - GA;
                int c = gg * 64 + l;
                gl_lds16(Bb + (size_t)(c >> 2) * Kb + (size_t)k0 * 2 + (c & 3) * 16,
                         (char*)&Bs[buf][0] + gg * 1024);
            }
        }
    };

    stage(0, 0);
    __syncthreads();
    int cur = 0;
    for (int k0 = 0; k0 < K; k0 += BK) {
        if (k0 + BK < K) stage(cur ^ 1, k0 + BK);
        short8v af[FM], bf[2];
#pragma unroll
        for (int mi = 0; mi < FM; mi++)
            af[mi] = *(const short8v*)&As[cur][(wm + mi * 16 + lrow) * BK + lk8];
#pragma unroll
        for (int ni = 0; ni < 2; ni++)
            bf[ni] = *(const short8v*)&Bs[cur][(wn + ni * 16 + lrow) * BK + lk8];
#pragma unroll
        for (int mi = 0; mi < FM; mi++)
#pragma unroll
            for (int ni = 0; ni < 2; ni++)
                acc[mi][ni] = __builtin_amdgcn_mfma_f32_16x16x32_bf16(
                    af[mi], bf[ni], acc[mi][ni], 0, 0, 0);
        __syncthreads();
        cur ^= 1;
    }

    const int lq = (l >> 4) * 4;
#pragma unroll
    for (int mi = 0; mi < FM; mi++) {
#pragma unroll
        for (int ni = 0; ni < 2; ni++) {
            int row0 = bm + wm + mi * 16 + lq;
            int col = bn + wn + ni * 16 + lrow;
            if (EPI == 0) {
                __hip_bfloat16* o = (__hip_bfloat16*)Cv;
#pragma unroll
                for (int r = 0; r < 4; r++)
                    o[(size_t)(row0 + r) * N + col] = __float2bfloat16(acc[mi][ni][r]);
            } else if (EPI == 1) {
                if (col < 512) {
                    __hip_bfloat16* o = (__hip_bfloat16*)Cv;
                    float bc = bias[col];
#pragma unroll
                    for (int r = 0; r < 4; r++)
                        o[(size_t)(row0 + r) * 512 + col] =
                            __float2bfloat16(softplus_f(acc[mi][ni][r] + bc));
                } else if (col < 528) {
#pragma unroll
                    for (int r = 0; r < 4; r++)
                        outB[(size_t)(row0 + r) * 16 + (col - 512)] = acc[mi][ni][r];
                } else if (col < 544) {
#pragma unroll
                    for (int r = 0; r < 4; r++)
                        outC[(size_t)(row0 + r) * 16 + (col - 528)] = acc[mi][ni][r];
                }
            } else {
                float* o = (float*)Cv;
#pragma unroll
                for (int r = 0; r < 4; r++)
                    o[(size_t)(row0 + r) * 256 + col] += acc[mi][ni][r];
            }
        }
    }
}

// ---------------- chunked selective scan (register-state form) ----------------
// grid: 1024 blocks = dtile(8) x chunk(16) x b(8); block = 256 threads.

// pass A: per-chunk local scan (h0=0), outputs h_end[b,c,d,s] and dtsum[b,c,d].
__global__ __launch_bounds__(256) void k_scanA(const __hip_bfloat16* __restrict__ xs,
                                               const __hip_bfloat16* __restrict__ dt,
                                               const float* __restrict__ Bin,
                                               const float* __restrict__ A_log,
                                               float* __restrict__ h_end,
                                               float* __restrict__ dtsum) {
    int bx = blockIdx.x;
    int dtile = bx & 7;
    int c = (bx >> 3) & 15;
    int b = bx >> 7;
    int lane = threadIdx.x & 63, wave = threadIdx.x >> 6;
    int d = dtile * 64 + lane;
    int s0 = wave * 4;

    float4 Ar = *(const float4*)&A_log[d * 16 + s0];
    float A0 = -__expf(Ar.x), A1 = -__expf(Ar.y), A2 = -__expf(Ar.z), A3 = -__expf(Ar.w);

    const size_t tok0 = (size_t)b * LQ + (size_t)c * CHLEN;
    const __hip_bfloat16* dt_p = dt + tok0 * 512 + d;
    const __hip_bfloat16* x_p  = xs + tok0 * 512 + d;
    const float* B_p = Bin + tok0 * 16 + s0;

    float h0 = 0.f, h1 = 0.f, h2 = 0.f, h3 = 0.f, dts = 0.f;

    const int U = 4;
    float dtA[U], xA[U]; float4 BA[U];
    float dtB[U], xB[U]; float4 BB[U];

    auto loadA = [&](int t0) {
#pragma unroll
        for (int j = 0; j < U; j++) {
            dtA[j] = __bfloat162float(dt_p[(size_t)(t0 + j) * 512]);
            xA[j]  = __bfloat162float(x_p[(size_t)(t0 + j) * 512]);
            BA[j]  = *(const float4*)&B_p[(size_t)(t0 + j) * 16];
        }
    };
    auto loadB = [&](int t0) {
#pragma unroll
        for (int j = 0; j < U; j++) {
            dtB[j] = __bfloat162float(dt_p[(size_t)(t0 + j) * 512]);
            xB[j]  = __bfloat162float(x_p[(size_t)(t0 + j) * 512]);
            BB[j]  = *(const float4*)&B_p[(size_t)(t0 + j) * 16];
        }
    };
    auto compA = [&]() {
#pragma unroll
        for (int j = 0; j < U; j++) {
            float dtv = dtA[j], u = dtv * xA[j];
            dts += dtv;
            h0 = fmaf(__expf(A0 * dtv), h0, u * BA[j].x);
            h1 = fmaf(__expf(A1 * dtv), h1, u * BA[j].y);
            h2 = fmaf(__expf(A2 * dtv), h2, u * BA[j].z);
            h3 = fmaf(__expf(A3 * dtv), h3, u * BA[j].w);
        }
    };
    auto compB = [&]() {
#pragma unroll
        for (int j = 0; j < U; j++) {
            float dtv = dtB[j], u = dtv * xB[j];
            dts += dtv;
            h0 = fmaf(__expf(A0 * dtv), h0, u * BB[j].x);
            h1 = fmaf(__expf(A1 * dtv), h1, u * BB[j].y);
            h2 = fmaf(__expf(A2 * dtv), h2, u * BB[j].z);
            h3 = fmaf(__expf(A3 * dtv), h3, u * BB[j].w);
        }
    };

    loadA(0);
    for (int t = 0; t < CHLEN; t += 2 * U) {
        loadB(t + U);
        compA();
        if (t + 2 * U < CHLEN) loadA(t + 2 * U);
        compB();
    }

    size_t cidx = (size_t)(b * NCHUNK + c) * 512 + d;
    *(float4*)&h_end[cidx * 16 + s0] = make_float4(h0, h1, h2, h3);
    if (wave == 0) dtsum[cidx] = dts;
}

// pass B: serial carry across 16 chunks per (b,d,s)
__global__ __launch_bounds__(256) void k_carry(const float* __restrict__ h_end,
                                               const float* __restrict__ dtsum,
                                               const float* __restrict__ A_log,
                                               float* __restrict__ H_in) {
    int idx = blockIdx.x * 256 + threadIdx.x;  // 65536 = 8*512*16
    int s = idx & 15;
    int d = (idx >> 4) & 511;
    int b = idx >> 13;
    float Av = -__expf(A_log[d * 16 + s]);
    float H = 0.f;
#pragma unroll
    for (int c = 0; c < NCHUNK; c++) {
        size_t cidx = (size_t)(b * NCHUNK + c) * 512 + d;
        H_in[cidx * 16 + s] = H;
        H = fmaf(__expf(Av * dtsum[cidx]), H, h_end[cidx * 16 + s]);
    }
}

// pass C: re-run recurrence with correct H_in, compute y + fused gate.
__global__ __launch_bounds__(256) void k_scanC(const __hip_bfloat16* __restrict__ xs,
                                               const __hip_bfloat16* __restrict__ dt,
                                               const float* __restrict__ Bin,
                                               const float* __restrict__ Cin,
                                               const float* __restrict__ A_log,
                                               const float* __restrict__ H_in,
                                               const __hip_bfloat16* __restrict__ xz,
                                               const float* __restrict__ Dv,
                                               __hip_bfloat16* __restrict__ y) {
    int bx = blockIdx.x;
    int dtile = bx & 7;
    int c = (bx >> 3) & 15;
    int b = bx >> 7;
    int lane = threadIdx.x & 63, wave = threadIdx.x >> 6;
    int sg = lane & 3, dl = lane >> 2;
    int d = dtile * 64 + wave * 16 + dl;
    int s0 = sg * 4;

    float4 Ar = *(const float4*)&A_log[d * 16 + s0];
    float A0 = -__expf(Ar.x), A1 = -__expf(Ar.y), A2 = -__expf(Ar.z), A3 = -__expf(Ar.w);

    size_t cidx = (size_t)(b * NCHUNK + c) * 512 + d;
    float4 Hv = *(const float4*)&H_in[cidx * 16 + s0];
    float h0 = Hv.x, h1 = Hv.y, h2 = Hv.z, h3 = Hv.w;
    float Dd = Dv[d];

    const size_t tok0 = (size_t)b * LQ + (size_t)c * CHLEN;
    const __hip_bfloat16* dt_p = dt + tok0 * 512 + d;
    const __hip_bfloat16* x_p  = xs + tok0 * 512 + d;
    const __hip_bfloat16* z_p  = xz + tok0 * 1024 + 512 + d;
    const float* B_p = Bin + tok0 * 16 + s0;
    const float* C_p = Cin + tok0 * 16 + s0;
    __hip_bfloat16* y_p = y + tok0 * 512 + d;

    const int U = 4;
    float dtA[U], xA[U], zA[U]; float4 BA[U], CA[U];
    float dtB[U], xB[U], zB[U]; float4 BB[U], CB[U];

    auto loadA = [&](int t0) {
#pragma unroll
        for (int j = 0; j < U; j++) {
            dtA[j] = __bfloat162float(dt_p[(size_t)(t0 + j) * 512]);
            xA[j]  = __bfloat162float(x_p[(size_t)(t0 + j) * 512]);
            zA[j]  = __bfloat162float(z_p[(size_t)(t0 + j) * 1024]);
            BA[j]  = *(const float4*)&B_p[(size_t)(t0 + j) * 16];
            CA[j]  = *(const float4*)&C_p[(size_t)(t0 + j) * 16];
        }
    };
    auto loadB = [&](int t0) {
#pragma unroll
        for (int j = 0; j < U; j++) {
            dtB[j] = __bfloat162float(dt_p[(size_t)(t0 + j) * 512]);
            xB[j]  = __bfloat162float(x_p[(size_t)(t0 + j) * 512]);
            zB[j]  = __bfloat162float(z_p[(size_t)(t0 + j) * 1024]);
            BB[j]  = *(const float4*)&B_p[(size_t)(t0 + j) * 16];
            CB[j]  = *(const float4*)&C_p[(size_t)(t0 + j) * 16];
        }
    };
    auto compA = [&](int t0) {
#pragma unroll
        for (int j = 0; j < U; j++) {
            float dtv = dtA[j], u = dtv * xA[j];
            h0 = fmaf(__expf(A0 * dtv), h0, u * BA[j].x);
            h1 = fmaf(__expf(A1 * dtv), h1, u * BA[j].y);
            h2 = fmaf(__expf(A2 * dtv), h2, u * BA[j].z);
            h3 = fmaf(__expf(A3 * dtv), h3, u * BA[j].w);
            float yp = h0 * CA[j].x + h1 * CA[j].y + h2 * CA[j].z + h3 * CA[j].w;
            yp += __shfl_xor(yp, 1);
            yp += __shfl_xor(yp, 2);
            if (sg == 0)
                y_p[(size_t)(t0 + j) * 512] =
                    __float2bfloat16((yp + Dd * xA[j]) * silu_f(zA[j]));
        }
    };
    auto compB = [&](int t0) {
#pragma unroll
        for (int j = 0; j < U; j++) {
            float dtv = dtB[j], u = dtv * xB[j];
            h0 = fmaf(__expf(A0 * dtv), h0, u * BB[j].x);
            h1 = fmaf(__expf(A1 * dtv), h1, u * BB[j].y);
            h2 = fmaf(__expf(A2 * dtv), h2, u * BB[j].z);
            h3 = fmaf(__expf(A3 * dtv), h3, u * BB[j].w);
            float yp = h0 * CB[j].x + h1 * CB[j].y + h2 * CB[j].z + h3 * CB[j].w;
            yp += __shfl_xor(yp, 1);
            yp += __shfl_xor(yp, 2);
            if (sg == 0)
                y_p[(size_t)(t0 + j) * 512] =
                    __float2bfloat16((yp + Dd * xB[j]) * silu_f(zB[j]));
        }
    };

    loadA(0);
    for (int t = 0; t < CHLEN; t += 2 * U) {
        loadB(t + U);
        compA(t);
        if (t + 2 * U < CHLEN) loadA(t + 2 * U);
        compB(t + U);
    }
}

// per-token mean/rstd for final LN
__global__ __launch_bounds__(256) void k_stats(const float* __restrict__ h,
                                               float2* __restrict__ stats) {
    int tok = blockIdx.x * 4 + (threadIdx.x >> 6);
    int lane = threadIdx.x & 63;
    float4 v = *(const float4*)&h[(size_t)tok * 256 + lane * 4];
    float sm = v.x + v.y + v.z + v.w;
    float sq = v.x * v.x + v.y * v.y + v.z * v.z + v.w * v.w;
#pragma unroll
    for (int o = 32; o; o >>= 1) {
        sm += __shfl_xor(sm, o);
        sq += __shfl_xor(sq, o);
    }
    if (lane == 0) {
        float m = sm * (1.f / 256.f);
        float var = sq * (1.f / 256.f) - m * m;
        stats[tok] = make_float2(m, rsqrtf(var + 1e-5f));
    }
}

__global__ __launch_bounds__(256) void k_out(const float* __restrict__ h,
                                             const float2* __restrict__ stats,
                                             const float* __restrict__ g,
                                             const float* __restrict__ bias,
                                             float* __restrict__ out) {
    int b = blockIdx.x >> 3;
    int chunk = blockIdx.x & 7;
    int d = threadIdx.x;
    float accv = 0.f;
    for (int l = chunk * 128; l < chunk * 128 + 128; l++) {
        float2 st = stats[b * 1024 + l];
        accv += (h[((size_t)b * 1024 + l) * 256 + d] - st.x) * st.y;
    }
    float res = accv * g[d] * (1.f / 1024.f);
    if (chunk == 0) res += bias[d];
    atomicAdd(&out[b * 256 + d], res);
}

// ---------------- launch ----------------

extern "C" void kernel_launch(void* const* d_in, const int* in_sizes, int n_in,
                              void* d_out, int out_size, void* d_ws, size_t ws_size,
                              hipStream_t stream) {
    const float* x       = (const float*)d_in[0];
    const float* w_in    = (const float*)d_in[1];
    const float* b_in    = (const float*)d_in[2];
    const float* ln_in_g = (const float*)d_in[3];
    const float* ln_in_b = (const float*)d_in[4];
    const float* ln_g    = (const float*)d_in[5];
    const float* ln_b    = (const float*)d_in[6];
    const float* W_inproj= (const float*)d_in[7];
    const float* conv_w  = (const float*)d_in[8];
    const float* conv_b  = (const float*)d_in[9];
    const float* W_dt    = (const float*)d_in[10];
    const float* b_dt    = (const float*)d_in[11];
    const float* W_B     = (const float*)d_in[12];
    const float* W_C     = (const float*)d_in[13];
    const float* A_log   = (const float*)d_in[14];
    const float* Dp      = (const float*)d_in[15];
    const float* W_out   = (const float*)d_in[16];
    const float* ln_f_g  = (const float*)d_in[17];
    const float* ln_f_b  = (const float*)d_in[18];

    float* out = (float*)d_out;

    char* p = (char*)d_ws;
    auto alloc = [&](size_t bytes) { char* r = p; p += (bytes + 255) & ~(size_t)255; return r; };

    float* h            = (float*)alloc((size_t)NTOK * 256 * 4);
    __hip_bfloat16* hn  = (__hip_bfloat16*)alloc((size_t)NTOK * 256 * 2);
    __hip_bfloat16* xz  = (__hip_bfloat16*)alloc((size_t)NTOK * 1024 * 2);
    __hip_bfloat16* xs  = (__hip_bfloat16*)alloc((size_t)NTOK * 512 * 2);
    __hip_bfloat16* dtb = (__hip_bfloat16*)alloc((size_t)NTOK * 512 * 2);
    float* Bin          = (float*)alloc((size_t)NTOK * 16 * 4);
    float* Cin          = (float*)alloc((size_t)NTOK * 16 * 4);
    __hip_bfloat16* yb  = (__hip_bfloat16*)alloc((size_t)NTOK * 512 * 2);
    float2* stats       = (float2*)alloc((size_t)NTOK * 8);
    float* h_end        = (float*)alloc((size_t)BQ * NCHUNK * 512 * 16 * 4);
    float* H_in         = (float*)alloc((size_t)BQ * NCHUNK * 512 * 16 * 4);
    float* dtsum        = (float*)alloc((size_t)BQ * NCHUNK * 512 * 4);
    __hip_bfloat16* W1p = (__hip_bfloat16*)alloc((size_t)NLAYER * 1024 * 256 * 2);
    __hip_bfloat16* W2p = (__hip_bfloat16*)alloc((size_t)NLAYER * 640 * 512 * 2);
    __hip_bfloat16* W3p = (__hip_bfloat16*)alloc((size_t)NLAYER * 256 * 512 * 2);

    hipMemsetAsync(d_out, 0, (size_t)out_size * sizeof(float), stream);
    hipMemsetAsync(W2p, 0, (size_t)NLAYER * 640 * 512 * 2, stream);

    k_tr<<<dim3(8, 32, NLAYER), 256, 0, stream>>>(W_inproj, W1p, 256, 1024, 256 * 1024, 1024 * 256);
    k_tr<<<dim3(16, 16, NLAYER), 256, 0, stream>>>(W_dt, W2p, 512, 512, 512 * 512, 640 * 512);
    k_tr<<<dim3(16, 1, NLAYER), 256, 0, stream>>>(W_B, W2p + (size_t)512 * 512, 512, 16, 512 * 16, 640 * 512);
    k_tr<<<dim3(16, 1, NLAYER), 256, 0, stream>>>(W_C, W2p + (size_t)528 * 512, 512, 16, 512 * 16, 640 * 512);
    k_tr<<<dim3(16, 8, NLAYER), 256, 0, stream>>>(W_out, W3p, 512, 256, 512 * 256, 256 * 512);

    k_inproj_ln<<<NTOK, 256, 0, stream>>>(x, w_in, b_in, ln_in_g, ln_in_b, h);

    for (int l = 0; l < NLAYER; l++) {
        k_ln<<<NTOK, 256, 0, stream>>>(h, ln_g + l * 256, ln_b + l * 256, hn);

        k_mfma<0, 128><<<dim3(64, 16), 256, 0, stream>>>(hn, W1p + (size_t)l * 1024 * 256, xz,
                                                         nullptr, nullptr, nullptr, 1024, 256);

        k_conv<<<(NTOK * 512) / 256, 256, 0, stream>>>(xz, conv_w + (size_t)l * 512 * 4,
                                                       conv_b + (size_t)l * 512, xs);

        k_mfma<1, 128><<<dim3(64, 9), 256, 0, stream>>>(xs, W2p + (size_t)l * 640 * 512, dtb,
                                                        b_dt + (size_t)l * 512, Bin, Cin, 576, 512);

        const float* Al = A_log + (size_t)l * 512 * 16;
        k_scanA<<<1024, 256, 0, stream>>>(xs, dtb, Bin, Al, h_end, dtsum);
        k_carry<<<256, 256, 0, stream>>>(h_end, dtsum, Al, H_in);
        k_scanC<<<1024, 256, 0, stream>>>(xs, dtb, Bin, Cin, Al, H_in, xz,
                                          Dp + (size_t)l * 512, yb);

        k_mfma<2, 64><<<dim3(128, 4), 256, 0, stream>>>(yb, W3p + (size_t)l * 256 * 512, h,
                                                        nullptr, nullptr, nullptr, 256, 512);
    }

    k_stats<<<NTOK / 4, 256, 0, stream>>>(h, stats);
    k_out<<<64, 256, 0, stream>>>(h, stats, ln_f_g, ln_f_b, out);
}